// Round 3
// baseline (8515.579 us; speedup 1.0000x reference)
//
#include <hip/hip_runtime.h>
#include <math.h>

// Problem constants
#define NN 40000
#define NE 256000

// Workspace layout (floats), total 61,640,000 floats = 246.6 MB
//  acc : 40000*1152 = 46,080,000   [r|b|l] scatter accumulators
//  hp  : 40000*384  = 15,360,000   projected node features; REUSED as hg
//        (safe: k_gemm_hg block i reads only hp rows 8i..8i+7 into LDS
//         before its barrier and writes only hg rows 8i..8i+7 after)
//  cls : 40000*5    =    200,000   softmax probs
static const size_t ACC_OFF = 0;
static const size_t HP_OFF  = 46080000;
static const size_t CLS_OFF = 61440000;
#define ACC_FLOATS 46080000

// ---------------------------------------------------------------------------
// Kernel Z: zero the scatter accumulator (ws is poisoned 0xAA each call)
// ---------------------------------------------------------------------------
__global__ __launch_bounds__(256) void k_zero(float4* __restrict__ p, int n4)
{
    int stride = gridDim.x * 256;
    for (int i = blockIdx.x * 256 + threadIdx.x; i < n4; i += stride)
        p[i] = make_float4(0.f, 0.f, 0.f, 0.f);
}

// ---------------------------------------------------------------------------
// Kernel A: fused projections  h[:, :300]@Wp0, h[:,300:384]@Wp1  + LN + relu
// 4 nodes / block, 192 threads (1 thread = 1 output column)
// ---------------------------------------------------------------------------
__global__ __launch_bounds__(192) void k_proj(
    const float* __restrict__ h,
    const float* __restrict__ Wp0, const float* __restrict__ bp0,
    const float* __restrict__ gp0, const float* __restrict__ bep0,
    const float* __restrict__ Wp1, const float* __restrict__ bp1,
    const float* __restrict__ gp1, const float* __restrict__ bep1,
    float* __restrict__ hp)
{
    __shared__ __align__(16) float hs[4 * 384];
    __shared__ float2 red0[4][3];
    __shared__ float2 red1[4][3];
    const int tid = threadIdx.x;
    const int n0 = blockIdx.x * 4;
    const float* srcp = h + (size_t)n0 * 384;
    for (int i = tid; i < 4 * 384; i += 192) hs[i] = srcp[i];
    __syncthreads();
    const int j = tid;
    const int wid = tid >> 6, lane = tid & 63;

    float a[4];
    // ---- chunk 0: 300 -> 192 ----
    {
        float b = bp0[j];
        a[0] = b; a[1] = b; a[2] = b; a[3] = b;
        #pragma unroll 4
        for (int k = 0; k < 300; ++k) {
            float w = Wp0[k * 192 + j];
            a[0] += hs[0 * 384 + k] * w;
            a[1] += hs[1 * 384 + k] * w;
            a[2] += hs[2 * 384 + k] * w;
            a[3] += hs[3 * 384 + k] * w;
        }
        float2 p[4];
        #pragma unroll
        for (int n = 0; n < 4; ++n) p[n] = make_float2(a[n], a[n] * a[n]);
        #pragma unroll
        for (int n = 0; n < 4; ++n)
            for (int o = 32; o > 0; o >>= 1) {
                p[n].x += __shfl_down(p[n].x, o);
                p[n].y += __shfl_down(p[n].y, o);
            }
        if (lane == 0) {
            red0[0][wid] = p[0]; red0[1][wid] = p[1];
            red0[2][wid] = p[2]; red0[3][wid] = p[3];
        }
        __syncthreads();
        float g = gp0[j], be = bep0[j];
        #pragma unroll
        for (int n = 0; n < 4; ++n) {
            float s  = red0[n][0].x + red0[n][1].x + red0[n][2].x;
            float sq = red0[n][0].y + red0[n][1].y + red0[n][2].y;
            float mu  = s * (1.0f / 192.0f);
            float var = sq * (1.0f / 192.0f) - mu * mu;
            float v = (a[n] - mu) * rsqrtf(var + 1e-5f) * g + be;
            hp[(size_t)(n0 + n) * 384 + j] = fmaxf(v, 0.0f);
        }
    }
    // ---- chunk 1: 84 -> 192 ----
    {
        float b = bp1[j];
        a[0] = b; a[1] = b; a[2] = b; a[3] = b;
        #pragma unroll 4
        for (int k = 0; k < 84; ++k) {
            float w = Wp1[k * 192 + j];
            a[0] += hs[0 * 384 + 300 + k] * w;
            a[1] += hs[1 * 384 + 300 + k] * w;
            a[2] += hs[2 * 384 + 300 + k] * w;
            a[3] += hs[3 * 384 + 300 + k] * w;
        }
        float2 p[4];
        #pragma unroll
        for (int n = 0; n < 4; ++n) p[n] = make_float2(a[n], a[n] * a[n]);
        #pragma unroll
        for (int n = 0; n < 4; ++n)
            for (int o = 32; o > 0; o >>= 1) {
                p[n].x += __shfl_down(p[n].x, o);
                p[n].y += __shfl_down(p[n].y, o);
            }
        if (lane == 0) {
            red1[0][wid] = p[0]; red1[1][wid] = p[1];
            red1[2][wid] = p[2]; red1[3][wid] = p[3];
        }
        __syncthreads();
        float g = gp1[j], be = bep1[j];
        #pragma unroll
        for (int n = 0; n < 4; ++n) {
            float s  = red1[n][0].x + red1[n][1].x + red1[n][2].x;
            float sq = red1[n][0].y + red1[n][1].y + red1[n][2].y;
            float mu  = s * (1.0f / 192.0f);
            float var = sq * (1.0f / 192.0f) - mu * mu;
            float v = (a[n] - mu) * rsqrtf(var + 1e-5f) * g + be;
            hp[(size_t)(n0 + n) * 384 + 192 + j] = fmaxf(v, 0.0f);
        }
    }
}

// ---------------------------------------------------------------------------
// Kernel B: edge scatter.  acc[dst][pos*384 + f] += hp[src][f] * dist
// pos==3 contributes nothing (reference computes directions 0,1,2 only;
// t = direction(0) is handled by reading the r slice twice in kernel C).
// 96 threads per edge, one float4 each.
// ---------------------------------------------------------------------------
__global__ __launch_bounds__(256) void k_scatter(
    const float* __restrict__ hp,
    const int* __restrict__ src, const int* __restrict__ dst,
    const int* __restrict__ pos, const float* __restrict__ dist,
    float* __restrict__ acc)
{
    int gid = blockIdx.x * 256 + threadIdx.x;   // NE*96 total
    int e  = gid / 96;
    int f4 = (gid - e * 96) * 4;
    int p = pos[e];
    if (p >= 3) return;
    float w = dist[e];
    int s = src[e], d = dst[e];
    const float4 v = *reinterpret_cast<const float4*>(&hp[(size_t)s * 384 + f4]);
    float* o = &acc[(size_t)d * 1152 + (size_t)p * 384 + f4];
    atomicAdd(o + 0, v.x * w);
    atomicAdd(o + 1, v.y * w);
    atomicAdd(o + 2, v.z * w);
    atomicAdd(o + 3, v.w * w);
}

// ---------------------------------------------------------------------------
// Kernel C: hg = relu(LN(hc @ Wg + bg)), hc = [hp, r, b, l, r] (1920)
// 8 nodes / block, 384 threads (1 thread = 1 output column).
// LDS x-tile stored [k][n] so compute reads are broadcast ds_read_b128.
// hg MAY ALIAS hp: block reads only its own 8 hp rows (into LDS, before the
// barrier) and writes only those same 8 hg rows afterward.
// ---------------------------------------------------------------------------
__global__ __launch_bounds__(384) void k_gemm_hg(
    const float* __restrict__ hp, const float* __restrict__ acc,
    const float* __restrict__ Wg, const float* __restrict__ bg,
    const float* __restrict__ gg, const float* __restrict__ beg,
    float* __restrict__ hg)
{
    __shared__ __align__(16) float xs[1920 * 8];   // [k][n]
    __shared__ float2 red[8][6];
    const int tid = threadIdx.x;
    const int n0 = blockIdx.x * 8;
    for (int i = tid; i < 8 * 384; i += 384) {
        int n = i / 384, k = i - n * 384;
        xs[k * 8 + n] = hp[(size_t)(n0 + n) * 384 + k];
    }
    for (int i = tid; i < 8 * 1152; i += 384) {
        int n = i / 1152, c = i - n * 1152;
        float v = acc[(size_t)(n0 + n) * 1152 + c];
        xs[(384 + c) * 8 + n] = v;
        if (c < 384) xs[(1536 + c) * 8 + n] = v;   // t = r duplicate
    }
    __syncthreads();
    const int j = tid;
    float a[8];
    {
        float b = bg[j];
        #pragma unroll
        for (int n = 0; n < 8; ++n) a[n] = b;
    }
    #pragma unroll 4
    for (int k = 0; k < 1920; ++k) {
        float w = Wg[k * 384 + j];
        const float4 x0 = *reinterpret_cast<const float4*>(&xs[k * 8 + 0]);
        const float4 x1 = *reinterpret_cast<const float4*>(&xs[k * 8 + 4]);
        a[0] += x0.x * w; a[1] += x0.y * w; a[2] += x0.z * w; a[3] += x0.w * w;
        a[4] += x1.x * w; a[5] += x1.y * w; a[6] += x1.z * w; a[7] += x1.w * w;
    }
    const int wid = tid >> 6, lane = tid & 63;
    float2 p[8];
    #pragma unroll
    for (int n = 0; n < 8; ++n) p[n] = make_float2(a[n], a[n] * a[n]);
    #pragma unroll
    for (int n = 0; n < 8; ++n)
        for (int o = 32; o > 0; o >>= 1) {
            p[n].x += __shfl_down(p[n].x, o);
            p[n].y += __shfl_down(p[n].y, o);
        }
    if (lane == 0) {
        #pragma unroll
        for (int n = 0; n < 8; ++n) red[n][wid] = p[n];
    }
    __syncthreads();
    float g = gg[j], be = beg[j];
    #pragma unroll
    for (int n = 0; n < 8; ++n) {
        float s = 0.0f, sq = 0.0f;
        #pragma unroll
        for (int w2 = 0; w2 < 6; ++w2) { s += red[n][w2].x; sq += red[n][w2].y; }
        float mu  = s * (1.0f / 384.0f);
        float var = sq * (1.0f / 384.0f) - mu * mu;
        float v = (a[n] - mu) * rsqrtf(var + 1e-5f) * g + be;
        hg[(size_t)(n0 + n) * 384 + j] = fmaxf(v, 0.0f);
    }
}

// ---------------------------------------------------------------------------
// Kernel D: n = LN(hg @ Wn + bn); cls = softmax(n).  1 wave / node.
// ---------------------------------------------------------------------------
__global__ __launch_bounds__(256) void k_node_head(
    const float* __restrict__ hg,
    const float* __restrict__ Wn, const float* __restrict__ bn,
    const float* __restrict__ gn, const float* __restrict__ ben,
    float* __restrict__ nout, float* __restrict__ cls)
{
    __shared__ float wns[384 * 5];
    const int tid = threadIdx.x;
    for (int i = tid; i < 1920; i += 256) wns[i] = Wn[i];
    __syncthreads();
    const int wid = tid >> 6, lane = tid & 63;
    const int node = blockIdx.x * 4 + wid;
    float a0 = 0, a1 = 0, a2 = 0, a3 = 0, a4 = 0;
    const float* row = hg + (size_t)node * 384;
    for (int k = lane; k < 384; k += 64) {
        float v = row[k];
        const float* wp = &wns[k * 5];
        a0 += v * wp[0]; a1 += v * wp[1]; a2 += v * wp[2];
        a3 += v * wp[3]; a4 += v * wp[4];
    }
    for (int o = 32; o > 0; o >>= 1) {
        a0 += __shfl_down(a0, o); a1 += __shfl_down(a1, o);
        a2 += __shfl_down(a2, o); a3 += __shfl_down(a3, o);
        a4 += __shfl_down(a4, o);
    }
    if (lane == 0) {
        float v[5] = { a0 + bn[0], a1 + bn[1], a2 + bn[2], a3 + bn[3], a4 + bn[4] };
        float mu = (v[0] + v[1] + v[2] + v[3] + v[4]) * 0.2f;
        float var = 0.0f;
        #pragma unroll
        for (int c = 0; c < 5; ++c) { float d = v[c] - mu; var += d * d; }
        var *= 0.2f;
        float rs = rsqrtf(var + 1e-5f);
        float nv[5]; float m = -1e30f;
        #pragma unroll
        for (int c = 0; c < 5; ++c) {
            nv[c] = (v[c] - mu) * rs * gn[c] + ben[c];
            m = fmaxf(m, nv[c]);
        }
        #pragma unroll
        for (int c = 0; c < 5; ++c) nout[(size_t)node * 5 + c] = nv[c];
        float ex[5]; float s = 0.0f;
        #pragma unroll
        for (int c = 0; c < 5; ++c) { ex[c] = expf(nv[c] - m); s += ex[c]; }
        float inv = 1.0f / s;
        #pragma unroll
        for (int c = 0; c < 5; ++c) cls[(size_t)node * 5 + c] = ex[c] * inv;
    }
}

// ---------------------------------------------------------------------------
// Kernel E: edge MLP.  x = [hg[src], cls[src], polar, hg[dst], cls[dst]] (784)
// e = relu(LN(x @ W1 + b1)) @ W2 + b2
// 16 edges / block, 320 threads (threads 0..299 own one W1 column).
// ---------------------------------------------------------------------------
__global__ __launch_bounds__(320) void k_edge_mlp(
    const float* __restrict__ hg, const float* __restrict__ cls,
    const int* __restrict__ srcI, const int* __restrict__ dstI,
    const float* __restrict__ polar,
    const float* __restrict__ W1, const float* __restrict__ b1,
    const float* __restrict__ g1, const float* __restrict__ be1,
    const float* __restrict__ W2, const float* __restrict__ b2,
    float* __restrict__ eout)
{
    __shared__ __align__(16) float xs[784 * 16];   // [c][e]
    __shared__ float2 redA[16][5];
    __shared__ float2 redB[16][5];
    const int tid = threadIdx.x;
    const int e0 = blockIdx.x * 16;
    for (int idx = tid; idx < 16 * 784; idx += 320) {
        int e = idx / 784, c = idx - e * 784;
        int eg = e0 + e;
        float v;
        if (c < 384)      v = hg[(size_t)srcI[eg] * 384 + c];
        else if (c < 389) v = cls[(size_t)srcI[eg] * 5 + (c - 384)];
        else if (c < 395) v = polar[(size_t)eg * 6 + (c - 389)];
        else if (c < 779) v = hg[(size_t)dstI[eg] * 384 + (c - 395)];
        else              v = cls[(size_t)dstI[eg] * 5 + (c - 779)];
        xs[c * 16 + e] = v;
    }
    __syncthreads();
    const int j = (tid < 300) ? tid : 299;        // clamp; extras masked below
    const float mask = (tid < 300) ? 1.0f : 0.0f;
    float a[16];
    {
        float b = b1[j];
        #pragma unroll
        for (int e = 0; e < 16; ++e) a[e] = b;
    }
    #pragma unroll 2
    for (int i = 0; i < 784; ++i) {
        float w = W1[i * 300 + j];
        const float4 x0 = *reinterpret_cast<const float4*>(&xs[i * 16 + 0]);
        const float4 x1 = *reinterpret_cast<const float4*>(&xs[i * 16 + 4]);
        const float4 x2 = *reinterpret_cast<const float4*>(&xs[i * 16 + 8]);
        const float4 x3 = *reinterpret_cast<const float4*>(&xs[i * 16 + 12]);
        a[0]  += x0.x * w; a[1]  += x0.y * w; a[2]  += x0.z * w; a[3]  += x0.w * w;
        a[4]  += x1.x * w; a[5]  += x1.y * w; a[6]  += x1.z * w; a[7]  += x1.w * w;
        a[8]  += x2.x * w; a[9]  += x2.y * w; a[10] += x2.z * w; a[11] += x2.w * w;
        a[12] += x3.x * w; a[13] += x3.y * w; a[14] += x3.z * w; a[15] += x3.w * w;
    }
    const int wid = tid >> 6, lane = tid & 63;
    // LayerNorm stats over the 300 columns of each edge
    {
        float2 p[16];
        #pragma unroll
        for (int e = 0; e < 16; ++e)
            p[e] = make_float2(mask * a[e], mask * a[e] * a[e]);
        #pragma unroll
        for (int e = 0; e < 16; ++e)
            for (int o = 32; o > 0; o >>= 1) {
                p[e].x += __shfl_down(p[e].x, o);
                p[e].y += __shfl_down(p[e].y, o);
            }
        if (lane == 0) {
            #pragma unroll
            for (int e = 0; e < 16; ++e) redA[e][wid] = p[e];
        }
    }
    __syncthreads();
    float g = g1[j], be = be1[j];
    float y[16];
    #pragma unroll
    for (int e = 0; e < 16; ++e) {
        float s = 0.0f, sq = 0.0f;
        #pragma unroll
        for (int w2 = 0; w2 < 5; ++w2) { s += redA[e][w2].x; sq += redA[e][w2].y; }
        float mu  = s * (1.0f / 300.0f);
        float var = sq * (1.0f / 300.0f) - mu * mu;
        float rs = rsqrtf(var + 1e-5f);
        y[e] = fmaxf((a[e] - mu) * rs * g + be, 0.0f) * mask;
    }
    // second layer: 300 -> 2, via block reduction
    {
        float w20 = W2[j * 2 + 0], w21 = W2[j * 2 + 1];
        float2 q[16];
        #pragma unroll
        for (int e = 0; e < 16; ++e) q[e] = make_float2(y[e] * w20, y[e] * w21);
        #pragma unroll
        for (int e = 0; e < 16; ++e)
            for (int o = 32; o > 0; o >>= 1) {
                q[e].x += __shfl_down(q[e].x, o);
                q[e].y += __shfl_down(q[e].y, o);
            }
        if (lane == 0) {
            #pragma unroll
            for (int e = 0; e < 16; ++e) redB[e][wid] = q[e];
        }
    }
    __syncthreads();
    if (tid == 0) {
        float bb0 = b2[0], bb1 = b2[1];
        #pragma unroll
        for (int e = 0; e < 16; ++e) {
            float o0 = bb0, o1 = bb1;
            #pragma unroll
            for (int w2 = 0; w2 < 5; ++w2) { o0 += redB[e][w2].x; o1 += redB[e][w2].y; }
            eout[(size_t)(e0 + e) * 2 + 0] = o0;
            eout[(size_t)(e0 + e) * 2 + 1] = o1;
        }
    }
}

// ---------------------------------------------------------------------------
extern "C" void kernel_launch(void* const* d_in, const int* in_sizes, int n_in,
                              void* d_out, int out_size, void* d_ws, size_t ws_size,
                              hipStream_t stream)
{
    const float* h     = (const float*)d_in[0];
    const int*   src   = (const int*)d_in[1];
    const int*   dst   = (const int*)d_in[2];
    const int*   pos   = (const int*)d_in[3];
    const float* dist  = (const float*)d_in[4];
    const float* polar = (const float*)d_in[5];
    const float* Wp0   = (const float*)d_in[6];
    const float* bp0   = (const float*)d_in[7];
    const float* gp0   = (const float*)d_in[8];
    const float* bep0  = (const float*)d_in[9];
    const float* Wp1   = (const float*)d_in[10];
    const float* bp1   = (const float*)d_in[11];
    const float* gp1   = (const float*)d_in[12];
    const float* bep1  = (const float*)d_in[13];
    const float* Wg    = (const float*)d_in[14];
    const float* bg    = (const float*)d_in[15];
    const float* gg    = (const float*)d_in[16];
    const float* beg   = (const float*)d_in[17];
    const float* Wn    = (const float*)d_in[18];
    const float* bn    = (const float*)d_in[19];
    const float* gn    = (const float*)d_in[20];
    const float* ben   = (const float*)d_in[21];
    const float* W1    = (const float*)d_in[22];
    const float* b1    = (const float*)d_in[23];
    const float* g1    = (const float*)d_in[24];
    const float* be1   = (const float*)d_in[25];
    const float* W2    = (const float*)d_in[26];
    const float* b2    = (const float*)d_in[27];

    float* ws  = (float*)d_ws;
    float* acc = ws + ACC_OFF;
    float* hp  = ws + HP_OFF;
    float* hg  = hp;                        // aliased (see k_gemm_hg comment)
    float* cls = ws + CLS_OFF;
    float* nout = (float*)d_out;            // 40000*5
    float* eout = (float*)d_out + 200000;   // 256000*2

    // zero the scatter accumulators with a kernel (no memset during capture)
    k_zero<<<2048, 256, 0, stream>>>((float4*)acc, ACC_FLOATS / 4);

    k_proj<<<10000, 192, 0, stream>>>(h, Wp0, bp0, gp0, bep0,
                                      Wp1, bp1, gp1, bep1, hp);
    k_scatter<<<96000, 256, 0, stream>>>(hp, src, dst, pos, dist, acc);
    k_gemm_hg<<<5000, 384, 0, stream>>>(hp, acc, Wg, bg, gg, beg, hg);
    k_node_head<<<10000, 256, 0, stream>>>(hg, Wn, bn, gn, ben, nout, cls);
    k_edge_mlp<<<16000, 320, 0, stream>>>(hg, cls, src, dst, polar,
                                          W1, b1, g1, be1, W2, b2, eout);
}

// Round 4
// 6778.470 us; speedup vs baseline: 1.2563x; 1.2563x over previous
//
#include <hip/hip_runtime.h>
#include <math.h>

// Problem constants
#define NN 40000
#define NE 256000

// Workspace layout (floats), total 61,640,000 floats = 246.6 MB
//  acc : 40000*1152 = 46,080,000   [r|b|l] scatter accumulators
//  hp  : 40000*384  = 15,360,000   projected node features; REUSED as hg
//  cls : 40000*5    =    200,000   softmax probs
static const size_t ACC_OFF = 0;
static const size_t HP_OFF  = 46080000;
static const size_t CLS_OFF = 61440000;
#define ACC_FLOATS 46080000

// ---------------------------------------------------------------------------
__global__ __launch_bounds__(256) void k_zero(float4* __restrict__ p, int n4)
{
    int stride = gridDim.x * 256;
    for (int i = blockIdx.x * 256 + threadIdx.x; i < n4; i += stride)
        p[i] = make_float4(0.f, 0.f, 0.f, 0.f);
}

// ---------------------------------------------------------------------------
// Kernel A: fused projections, register-blocked.
// 16 nodes/block, 192 threads: jg = tid%48 owns j = jg*4..+3 (Jr=4),
// nt = tid/48 owns nodes nt*4..+3 (Nr=4).  Per k: 1 ds_read_b128 (4 nodes)
// + 1 coalesced W float4 + 16 FMA  -> FMA:LDS = 16:1 (was 1:1).
// ---------------------------------------------------------------------------
__global__ __launch_bounds__(192) void k_proj(
    const float* __restrict__ h,
    const float* __restrict__ Wp0, const float* __restrict__ bp0,
    const float* __restrict__ gp0, const float* __restrict__ bep0,
    const float* __restrict__ Wp1, const float* __restrict__ bp1,
    const float* __restrict__ gp1, const float* __restrict__ bep1,
    float* __restrict__ hp)
{
    __shared__ __align__(16) float xs[384 * 16];   // [c][n], 24.6 KB
    __shared__ float2 stats0[16], stats1[16];
    const int tid = threadIdx.x;
    const int n0  = blockIdx.x * 16;
    const int jg  = tid % 48;           // 48 groups * 4 j = 192
    const int nt  = tid / 48;           // 4 groups * 4 nodes = 16
    const int j0  = jg * 4;

    // stage: n-fastest -> conflict-free LDS writes
    for (int idx = tid; idx < 384 * 16; idx += 192) {
        int n = idx & 15, c = idx >> 4;
        xs[c * 16 + n] = h[(size_t)(n0 + n) * 384 + c];
    }
    __syncthreads();

    float a0[4][4], a1[4][4];           // [j][n]
    #pragma unroll
    for (int r = 0; r < 4; ++r)
        #pragma unroll
        for (int n = 0; n < 4; ++n) { a0[r][n] = 0.f; a1[r][n] = 0.f; }

    #pragma unroll 2
    for (int k = 0; k < 300; ++k) {
        const float4 x = *reinterpret_cast<const float4*>(&xs[k * 16 + nt * 4]);
        const float4 w = *reinterpret_cast<const float4*>(&Wp0[k * 192 + j0]);
        const float wr[4] = { w.x, w.y, w.z, w.w };
        const float xr[4] = { x.x, x.y, x.z, x.w };
        #pragma unroll
        for (int r = 0; r < 4; ++r)
            #pragma unroll
            for (int n = 0; n < 4; ++n) a0[r][n] += wr[r] * xr[n];
    }
    #pragma unroll 2
    for (int k = 0; k < 84; ++k) {
        const float4 x = *reinterpret_cast<const float4*>(&xs[(300 + k) * 16 + nt * 4]);
        const float4 w = *reinterpret_cast<const float4*>(&Wp1[k * 192 + j0]);
        const float wr[4] = { w.x, w.y, w.z, w.w };
        const float xr[4] = { x.x, x.y, x.z, x.w };
        #pragma unroll
        for (int r = 0; r < 4; ++r)
            #pragma unroll
            for (int n = 0; n < 4; ++n) a1[r][n] += wr[r] * xr[n];
    }
    // add bias
    {
        const float4 b0 = *reinterpret_cast<const float4*>(&bp0[j0]);
        const float4 b1 = *reinterpret_cast<const float4*>(&bp1[j0]);
        const float b0r[4] = { b0.x, b0.y, b0.z, b0.w };
        const float b1r[4] = { b1.x, b1.y, b1.z, b1.w };
        #pragma unroll
        for (int r = 0; r < 4; ++r)
            #pragma unroll
            for (int n = 0; n < 4; ++n) { a0[r][n] += b0r[r]; a1[r][n] += b1r[r]; }
    }
    __syncthreads();                    // xs dead -> overlay reductions
    float2* red = (float2*)xs;          // [jg][16 n]

    // ---- LN chunk 0 ----
    #pragma unroll
    for (int n = 0; n < 4; ++n) {
        float s = 0.f, q = 0.f;
        #pragma unroll
        for (int r = 0; r < 4; ++r) { s += a0[r][n]; q += a0[r][n] * a0[r][n]; }
        red[jg * 16 + nt * 4 + n] = make_float2(s, q);
    }
    __syncthreads();
    if (tid < 16) {
        float s = 0.f, q = 0.f;
        for (int g = 0; g < 48; ++g) { float2 v = red[g * 16 + tid]; s += v.x; q += v.y; }
        float mu = s * (1.f / 192.f);
        float var = q * (1.f / 192.f) - mu * mu;
        stats0[tid] = make_float2(mu, rsqrtf(var + 1e-5f));
    }
    __syncthreads();
    // ---- LN chunk 1 partials (red chunk0 dead) ----
    #pragma unroll
    for (int n = 0; n < 4; ++n) {
        float s = 0.f, q = 0.f;
        #pragma unroll
        for (int r = 0; r < 4; ++r) { s += a1[r][n]; q += a1[r][n] * a1[r][n]; }
        red[jg * 16 + nt * 4 + n] = make_float2(s, q);
    }
    // ---- write chunk 0 ----
    {
        const float4 g = *reinterpret_cast<const float4*>(&gp0[j0]);
        const float4 be = *reinterpret_cast<const float4*>(&bep0[j0]);
        const float gr[4] = { g.x, g.y, g.z, g.w };
        const float br[4] = { be.x, be.y, be.z, be.w };
        #pragma unroll
        for (int n = 0; n < 4; ++n) {
            float2 st = stats0[nt * 4 + n];
            float4 o;
            o.x = fmaxf((a0[0][n] - st.x) * st.y * gr[0] + br[0], 0.f);
            o.y = fmaxf((a0[1][n] - st.x) * st.y * gr[1] + br[1], 0.f);
            o.z = fmaxf((a0[2][n] - st.x) * st.y * gr[2] + br[2], 0.f);
            o.w = fmaxf((a0[3][n] - st.x) * st.y * gr[3] + br[3], 0.f);
            *reinterpret_cast<float4*>(&hp[(size_t)(n0 + nt * 4 + n) * 384 + j0]) = o;
        }
    }
    __syncthreads();
    if (tid < 16) {
        float s = 0.f, q = 0.f;
        for (int g = 0; g < 48; ++g) { float2 v = red[g * 16 + tid]; s += v.x; q += v.y; }
        float mu = s * (1.f / 192.f);
        float var = q * (1.f / 192.f) - mu * mu;
        stats1[tid] = make_float2(mu, rsqrtf(var + 1e-5f));
    }
    __syncthreads();
    {
        const float4 g = *reinterpret_cast<const float4*>(&gp1[j0]);
        const float4 be = *reinterpret_cast<const float4*>(&bep1[j0]);
        const float gr[4] = { g.x, g.y, g.z, g.w };
        const float br[4] = { be.x, be.y, be.z, be.w };
        #pragma unroll
        for (int n = 0; n < 4; ++n) {
            float2 st = stats1[nt * 4 + n];
            float4 o;
            o.x = fmaxf((a1[0][n] - st.x) * st.y * gr[0] + br[0], 0.f);
            o.y = fmaxf((a1[1][n] - st.x) * st.y * gr[1] + br[1], 0.f);
            o.z = fmaxf((a1[2][n] - st.x) * st.y * gr[2] + br[2], 0.f);
            o.w = fmaxf((a1[3][n] - st.x) * st.y * gr[3] + br[3], 0.f);
            *reinterpret_cast<float4*>(&hp[(size_t)(n0 + nt * 4 + n) * 384 + 192 + j0]) = o;
        }
    }
}

// ---------------------------------------------------------------------------
// Kernel B: edge scatter (unchanged).
// ---------------------------------------------------------------------------
__global__ __launch_bounds__(256) void k_scatter(
    const float* __restrict__ hp,
    const int* __restrict__ src, const int* __restrict__ dst,
    const int* __restrict__ pos, const float* __restrict__ dist,
    float* __restrict__ acc)
{
    int gid = blockIdx.x * 256 + threadIdx.x;   // NE*96 total
    int e  = gid / 96;
    int f4 = (gid - e * 96) * 4;
    int p = pos[e];
    if (p >= 3) return;
    float w = dist[e];
    int s = src[e], d = dst[e];
    const float4 v = *reinterpret_cast<const float4*>(&hp[(size_t)s * 384 + f4]);
    float* o = &acc[(size_t)d * 1152 + (size_t)p * 384 + f4];
    atomicAdd(o + 0, v.x * w);
    atomicAdd(o + 1, v.y * w);
    atomicAdd(o + 2, v.z * w);
    atomicAdd(o + 3, v.w * w);
}

// ---------------------------------------------------------------------------
// Kernel C: hg = relu(LN(hc @ Wg + bg)), hc = [hp, r, b, l, r] (K=1920).
// 8 nodes/block, 128 threads: jg = tid%64 owns j = jg*6..+5 (Jr=6),
// nt = tid/64 owns nodes nt*4..+3 (Nr=4).  K tiled 3x640 (20.5 KB LDS).
// Per k: 1 ds_read_b128 + 3 float2 W loads + 24 FMA -> FMA:LDS = 24:1.
// hg MAY ALIAS hp (block reads its 8 rows before writing them).
// ---------------------------------------------------------------------------
__global__ __launch_bounds__(128) void k_gemm_hg(
    const float* __restrict__ hp, const float* __restrict__ acc,
    const float* __restrict__ Wg, const float* __restrict__ bg,
    const float* __restrict__ gg, const float* __restrict__ beg,
    float* __restrict__ hg)
{
    __shared__ __align__(16) float xs[640 * 8];    // [c][n], 20.5 KB
    __shared__ float2 stats[8];
    const int tid = threadIdx.x;
    const int n0  = blockIdx.x * 8;
    const int jg  = tid & 63;           // 64 groups * 6 j = 384
    const int nt  = tid >> 6;           // 2 groups * 4 nodes = 8
    const int j0  = jg * 6;

    float a[6][4];                      // [j][n]
    #pragma unroll
    for (int r = 0; r < 6; ++r)
        #pragma unroll
        for (int n = 0; n < 4; ++n) a[r][n] = 0.f;

    for (int t = 0; t < 3; ++t) {
        // stage tile: columns cg = t*640 .. t*640+639 of hc
        for (int idx = tid; idx < 640 * 8; idx += 128) {
            int n = idx & 7, cl = idx >> 3;
            int cg = t * 640 + cl;
            float v;
            if (cg < 384)       v = hp[(size_t)(n0 + n) * 384 + cg];
            else if (cg < 1536) v = acc[(size_t)(n0 + n) * 1152 + (cg - 384)];
            else                v = acc[(size_t)(n0 + n) * 1152 + (cg - 1536)]; // t = r
            xs[cl * 8 + n] = v;
        }
        __syncthreads();
        const float* wrow = Wg + (size_t)t * 640 * 384;
        #pragma unroll 2
        for (int k = 0; k < 640; ++k) {
            const float4 x = *reinterpret_cast<const float4*>(&xs[k * 8 + nt * 4]);
            const float* wp = &wrow[(size_t)k * 384 + j0];
            const float2 w0 = *reinterpret_cast<const float2*>(wp + 0);
            const float2 w1 = *reinterpret_cast<const float2*>(wp + 2);
            const float2 w2 = *reinterpret_cast<const float2*>(wp + 4);
            const float wr[6] = { w0.x, w0.y, w1.x, w1.y, w2.x, w2.y };
            const float xr[4] = { x.x, x.y, x.z, x.w };
            #pragma unroll
            for (int r = 0; r < 6; ++r)
                #pragma unroll
                for (int n = 0; n < 4; ++n) a[r][n] += wr[r] * xr[n];
        }
        __syncthreads();
    }
    // bias
    #pragma unroll
    for (int r = 0; r < 6; ++r) {
        float b = bg[j0 + r];
        #pragma unroll
        for (int n = 0; n < 4; ++n) a[r][n] += b;
    }
    float2* red = (float2*)xs;          // overlay: [jg][8 n]
    #pragma unroll
    for (int n = 0; n < 4; ++n) {
        float s = 0.f, q = 0.f;
        #pragma unroll
        for (int r = 0; r < 6; ++r) { s += a[r][n]; q += a[r][n] * a[r][n]; }
        red[jg * 8 + nt * 4 + n] = make_float2(s, q);
    }
    __syncthreads();
    if (tid < 8) {
        float s = 0.f, q = 0.f;
        for (int g = 0; g < 64; ++g) { float2 v = red[g * 8 + tid]; s += v.x; q += v.y; }
        float mu = s * (1.f / 384.f);
        float var = q * (1.f / 384.f) - mu * mu;
        stats[tid] = make_float2(mu, rsqrtf(var + 1e-5f));
    }
    __syncthreads();
    #pragma unroll
    for (int n = 0; n < 4; ++n) {
        float2 st = stats[nt * 4 + n];
        float* orow = &hg[(size_t)(n0 + nt * 4 + n) * 384 + j0];
        #pragma unroll
        for (int r = 0; r < 6; ++r) {
            float v = (a[r][n] - st.x) * st.y * gg[j0 + r] + beg[j0 + r];
            orow[r] = fmaxf(v, 0.f);
        }
    }
}

// ---------------------------------------------------------------------------
// Kernel D: n = LN(hg @ Wn + bn); cls = softmax(n).  1 wave / node.
// ---------------------------------------------------------------------------
__global__ __launch_bounds__(256) void k_node_head(
    const float* __restrict__ hg,
    const float* __restrict__ Wn, const float* __restrict__ bn,
    const float* __restrict__ gn, const float* __restrict__ ben,
    float* __restrict__ nout, float* __restrict__ cls)
{
    __shared__ float wns[384 * 5];
    const int tid = threadIdx.x;
    for (int i = tid; i < 1920; i += 256) wns[i] = Wn[i];
    __syncthreads();
    const int wid = tid >> 6, lane = tid & 63;
    const int node = blockIdx.x * 4 + wid;
    float a0 = 0, a1 = 0, a2 = 0, a3 = 0, a4 = 0;
    const float* row = hg + (size_t)node * 384;
    for (int k = lane; k < 384; k += 64) {
        float v = row[k];
        const float* wp = &wns[k * 5];
        a0 += v * wp[0]; a1 += v * wp[1]; a2 += v * wp[2];
        a3 += v * wp[3]; a4 += v * wp[4];
    }
    for (int o = 32; o > 0; o >>= 1) {
        a0 += __shfl_down(a0, o); a1 += __shfl_down(a1, o);
        a2 += __shfl_down(a2, o); a3 += __shfl_down(a3, o);
        a4 += __shfl_down(a4, o);
    }
    if (lane == 0) {
        float v[5] = { a0 + bn[0], a1 + bn[1], a2 + bn[2], a3 + bn[3], a4 + bn[4] };
        float mu = (v[0] + v[1] + v[2] + v[3] + v[4]) * 0.2f;
        float var = 0.0f;
        #pragma unroll
        for (int c = 0; c < 5; ++c) { float d = v[c] - mu; var += d * d; }
        var *= 0.2f;
        float rs = rsqrtf(var + 1e-5f);
        float nv[5]; float m = -1e30f;
        #pragma unroll
        for (int c = 0; c < 5; ++c) {
            nv[c] = (v[c] - mu) * rs * gn[c] + ben[c];
            m = fmaxf(m, nv[c]);
        }
        #pragma unroll
        for (int c = 0; c < 5; ++c) nout[(size_t)node * 5 + c] = nv[c];
        float ex[5]; float s = 0.0f;
        #pragma unroll
        for (int c = 0; c < 5; ++c) { ex[c] = expf(nv[c] - m); s += ex[c]; }
        float inv = 1.0f / s;
        #pragma unroll
        for (int c = 0; c < 5; ++c) cls[(size_t)node * 5 + c] = ex[c] * inv;
    }
}

// ---------------------------------------------------------------------------
// Kernel E: edge MLP, register-blocked.
// 16 edges/block, 320 threads: et = tid/80 owns edges et*4..+3 (Er=4),
// jg = tid%80 owns j = jg*4..+3 (Jr=4, active jg<75 -> 300 cols).
// Per k: 1 ds_read_b128 + 1 coalesced W float4 + 16 FMA -> 16:1.
// Staging e-fastest -> conflict-free LDS writes.
// ---------------------------------------------------------------------------
__global__ __launch_bounds__(320) void k_edge_mlp(
    const float* __restrict__ hg, const float* __restrict__ cls,
    const int* __restrict__ srcI, const int* __restrict__ dstI,
    const float* __restrict__ polar,
    const float* __restrict__ W1, const float* __restrict__ b1,
    const float* __restrict__ g1, const float* __restrict__ be1,
    const float* __restrict__ W2, const float* __restrict__ b2,
    float* __restrict__ eout)
{
    __shared__ __align__(16) float xs[784 * 16];   // [c][e], 50.2 KB
    __shared__ float2 stats[16];
    const int tid = threadIdx.x;
    const int e0  = blockIdx.x * 16;
    const int et  = tid / 80;            // 4 edge-threads
    const int jg  = tid % 80;            // 80 j-groups, 75 active
    const bool act = (jg < 75);
    const int j0  = act ? jg * 4 : 0;    // clamped for masked threads

    // ---- stage x tile, e-fastest (conflict-free writes) ----
    {
        const int e  = tid & 15;
        const int eg = e0 + e;
        const int se = srcI[eg], de = dstI[eg];
        for (int idx = tid; idx < 784 * 16; idx += 320) {
            int c = idx >> 4;
            float v;
            if (c < 384)      v = hg[(size_t)se * 384 + c];
            else if (c < 389) v = cls[(size_t)se * 5 + (c - 384)];
            else if (c < 395) v = polar[(size_t)eg * 6 + (c - 389)];
            else if (c < 779) v = hg[(size_t)de * 384 + (c - 395)];
            else              v = cls[(size_t)de * 5 + (c - 779)];
            xs[c * 16 + e] = v;
        }
    }
    __syncthreads();

    // ---- layer 1 GEMM ----
    float a[4][4];                       // [j][e]
    #pragma unroll
    for (int r = 0; r < 4; ++r)
        #pragma unroll
        for (int e = 0; e < 4; ++e) a[r][e] = 0.f;

    #pragma unroll 2
    for (int k = 0; k < 784; ++k) {
        const float4 x = *reinterpret_cast<const float4*>(&xs[k * 16 + et * 4]);
        const float4 w = *reinterpret_cast<const float4*>(&W1[(size_t)k * 300 + j0]);
        const float wr[4] = { w.x, w.y, w.z, w.w };
        const float xr[4] = { x.x, x.y, x.z, x.w };
        #pragma unroll
        for (int r = 0; r < 4; ++r)
            #pragma unroll
            for (int e = 0; e < 4; ++e) a[r][e] += wr[r] * xr[e];
    }
    {
        const float4 b = *reinterpret_cast<const float4*>(&b1[j0]);
        const float br[4] = { b.x, b.y, b.z, b.w };
        #pragma unroll
        for (int r = 0; r < 4; ++r)
            #pragma unroll
            for (int e = 0; e < 4; ++e) a[r][e] += br[r];
    }
    __syncthreads();                     // xs dead -> overlay
    float2* red = (float2*)xs;           // [jg][16 e]

    // ---- LN stats over 300 j per edge ----
    if (act) {
        #pragma unroll
        for (int e = 0; e < 4; ++e) {
            float s = 0.f, q = 0.f;
            #pragma unroll
            for (int r = 0; r < 4; ++r) { s += a[r][e]; q += a[r][e] * a[r][e]; }
            red[jg * 16 + et * 4 + e] = make_float2(s, q);
        }
    }
    __syncthreads();
    if (tid < 16) {
        float s = 0.f, q = 0.f;
        for (int g = 0; g < 75; ++g) { float2 v = red[g * 16 + tid]; s += v.x; q += v.y; }
        float mu = s * (1.f / 300.f);
        float var = q * (1.f / 300.f) - mu * mu;
        stats[tid] = make_float2(mu, rsqrtf(var + 1e-5f));
    }
    __syncthreads();

    // ---- LN + relu + layer-2 partials ----
    const float4 g4  = *reinterpret_cast<const float4*>(&g1[j0]);
    const float4 be4 = *reinterpret_cast<const float4*>(&be1[j0]);
    const float4 w2a = *reinterpret_cast<const float4*>(&W2[j0 * 2]);     // j0,j0+1
    const float4 w2b = *reinterpret_cast<const float4*>(&W2[j0 * 2 + 4]); // j0+2,j0+3
    const float gr[4]  = { g4.x, g4.y, g4.z, g4.w };
    const float br[4]  = { be4.x, be4.y, be4.z, be4.w };
    const float w20[4] = { w2a.x, w2a.z, w2b.x, w2b.z };
    const float w21[4] = { w2a.y, w2a.w, w2b.y, w2b.w };
    float o0[4], o1[4];
    #pragma unroll
    for (int e = 0; e < 4; ++e) {
        float2 st = stats[et * 4 + e];
        float s0 = 0.f, s1 = 0.f;
        #pragma unroll
        for (int r = 0; r < 4; ++r) {
            float y = fmaxf((a[r][e] - st.x) * st.y * gr[r] + br[r], 0.f);
            s0 += y * w20[r];
            s1 += y * w21[r];
        }
        o0[e] = s0; o1[e] = s1;
    }
    // red region reuse for layer-2 reduction (red consumed by stats)
    if (act) {
        #pragma unroll
        for (int e = 0; e < 4; ++e)
            red[jg * 16 + et * 4 + e] = make_float2(o0[e], o1[e]);
    }
    __syncthreads();
    if (tid < 32) {
        int e = tid >> 1, c = tid & 1;
        float s = 0.f;
        for (int g = 0; g < 75; ++g) {
            float2 v = red[g * 16 + e];
            s += (c == 0) ? v.x : v.y;
        }
        eout[(size_t)(e0 + e) * 2 + c] = s + b2[c];
    }
}

// ---------------------------------------------------------------------------
extern "C" void kernel_launch(void* const* d_in, const int* in_sizes, int n_in,
                              void* d_out, int out_size, void* d_ws, size_t ws_size,
                              hipStream_t stream)
{
    const float* h     = (const float*)d_in[0];
    const int*   src   = (const int*)d_in[1];
    const int*   dst   = (const int*)d_in[2];
    const int*   pos   = (const int*)d_in[3];
    const float* dist  = (const float*)d_in[4];
    const float* polar = (const float*)d_in[5];
    const float* Wp0   = (const float*)d_in[6];
    const float* bp0   = (const float*)d_in[7];
    const float* gp0   = (const float*)d_in[8];
    const float* bep0  = (const float*)d_in[9];
    const float* Wp1   = (const float*)d_in[10];
    const float* bp1   = (const float*)d_in[11];
    const float* gp1   = (const float*)d_in[12];
    const float* bep1  = (const float*)d_in[13];
    const float* Wg    = (const float*)d_in[14];
    const float* bg    = (const float*)d_in[15];
    const float* gg    = (const float*)d_in[16];
    const float* beg   = (const float*)d_in[17];
    const float* Wn    = (const float*)d_in[18];
    const float* bn    = (const float*)d_in[19];
    const float* gn    = (const float*)d_in[20];
    const float* ben   = (const float*)d_in[21];
    const float* W1    = (const float*)d_in[22];
    const float* b1    = (const float*)d_in[23];
    const float* g1    = (const float*)d_in[24];
    const float* be1   = (const float*)d_in[25];
    const float* W2    = (const float*)d_in[26];
    const float* b2    = (const float*)d_in[27];

    float* ws  = (float*)d_ws;
    float* acc = ws + ACC_OFF;
    float* hp  = ws + HP_OFF;
    float* hg  = hp;                        // aliased (see k_gemm_hg comment)
    float* cls = ws + CLS_OFF;
    float* nout = (float*)d_out;            // 40000*5
    float* eout = (float*)d_out + 200000;   // 256000*2

    k_zero<<<2048, 256, 0, stream>>>((float4*)acc, ACC_FLOATS / 4);

    k_proj<<<2500, 192, 0, stream>>>(h, Wp0, bp0, gp0, bep0,
                                     Wp1, bp1, gp1, bep1, hp);
    k_scatter<<<96000, 256, 0, stream>>>(hp, src, dst, pos, dist, acc);
    k_gemm_hg<<<5000, 128, 0, stream>>>(hp, acc, Wg, bg, gg, beg, hg);
    k_node_head<<<10000, 256, 0, stream>>>(hg, Wn, bn, gn, ben, nout, cls);
    k_edge_mlp<<<16000, 320, 0, stream>>>(hg, cls, src, dst, polar,
                                          W1, b1, g1, be1, W2, b2, eout);
}

// Round 5
// 5489.035 us; speedup vs baseline: 1.5514x; 1.2349x over previous
//
#include <hip/hip_runtime.h>
#include <math.h>

// Problem constants
#define NN 40000
#define NE 256000

// Workspace layout (floats), total 61,640,000 floats = 246.6 MB
//  acc : 40000*1152 = 46,080,000   [r|b|l] scatter accumulators
//  hp  : 40000*384  = 15,360,000   projected node features; REUSED as hg
//  cls : 40000*5    =    200,000   softmax probs
static const size_t ACC_OFF = 0;
static const size_t HP_OFF  = 46080000;
static const size_t CLS_OFF = 61440000;
#define ACC_FLOATS 46080000

// ---------------------------------------------------------------------------
__global__ __launch_bounds__(256) void k_zero(float4* __restrict__ p, int n4)
{
    int stride = gridDim.x * 256;
    for (int i = blockIdx.x * 256 + threadIdx.x; i < n4; i += stride)
        p[i] = make_float4(0.f, 0.f, 0.f, 0.f);
}

// ---------------------------------------------------------------------------
// Kernel A: fused projections, register-blocked (unchanged from R4).
// 16 nodes/block, 192 threads, Jr=4 x Nr=4.
// ---------------------------------------------------------------------------
__global__ __launch_bounds__(192) void k_proj(
    const float* __restrict__ h,
    const float* __restrict__ Wp0, const float* __restrict__ bp0,
    const float* __restrict__ gp0, const float* __restrict__ bep0,
    const float* __restrict__ Wp1, const float* __restrict__ bp1,
    const float* __restrict__ gp1, const float* __restrict__ bep1,
    float* __restrict__ hp)
{
    __shared__ __align__(16) float xs[384 * 16];   // [c][n], 24.6 KB
    __shared__ float2 stats0[16], stats1[16];
    const int tid = threadIdx.x;
    const int n0  = blockIdx.x * 16;
    const int jg  = tid % 48;
    const int nt  = tid / 48;
    const int j0  = jg * 4;

    for (int idx = tid; idx < 384 * 16; idx += 192) {
        int n = idx & 15, c = idx >> 4;
        xs[c * 16 + n] = h[(size_t)(n0 + n) * 384 + c];
    }
    __syncthreads();

    float a0[4][4], a1[4][4];
    #pragma unroll
    for (int r = 0; r < 4; ++r)
        #pragma unroll
        for (int n = 0; n < 4; ++n) { a0[r][n] = 0.f; a1[r][n] = 0.f; }

    #pragma unroll 2
    for (int k = 0; k < 300; ++k) {
        const float4 x = *reinterpret_cast<const float4*>(&xs[k * 16 + nt * 4]);
        const float4 w = *reinterpret_cast<const float4*>(&Wp0[k * 192 + j0]);
        const float wr[4] = { w.x, w.y, w.z, w.w };
        const float xr[4] = { x.x, x.y, x.z, x.w };
        #pragma unroll
        for (int r = 0; r < 4; ++r)
            #pragma unroll
            for (int n = 0; n < 4; ++n) a0[r][n] += wr[r] * xr[n];
    }
    #pragma unroll 2
    for (int k = 0; k < 84; ++k) {
        const float4 x = *reinterpret_cast<const float4*>(&xs[(300 + k) * 16 + nt * 4]);
        const float4 w = *reinterpret_cast<const float4*>(&Wp1[k * 192 + j0]);
        const float wr[4] = { w.x, w.y, w.z, w.w };
        const float xr[4] = { x.x, x.y, x.z, x.w };
        #pragma unroll
        for (int r = 0; r < 4; ++r)
            #pragma unroll
            for (int n = 0; n < 4; ++n) a1[r][n] += wr[r] * xr[n];
    }
    {
        const float4 b0 = *reinterpret_cast<const float4*>(&bp0[j0]);
        const float4 b1 = *reinterpret_cast<const float4*>(&bp1[j0]);
        const float b0r[4] = { b0.x, b0.y, b0.z, b0.w };
        const float b1r[4] = { b1.x, b1.y, b1.z, b1.w };
        #pragma unroll
        for (int r = 0; r < 4; ++r)
            #pragma unroll
            for (int n = 0; n < 4; ++n) { a0[r][n] += b0r[r]; a1[r][n] += b1r[r]; }
    }
    __syncthreads();
    float2* red = (float2*)xs;

    #pragma unroll
    for (int n = 0; n < 4; ++n) {
        float s = 0.f, q = 0.f;
        #pragma unroll
        for (int r = 0; r < 4; ++r) { s += a0[r][n]; q += a0[r][n] * a0[r][n]; }
        red[jg * 16 + nt * 4 + n] = make_float2(s, q);
    }
    __syncthreads();
    if (tid < 16) {
        float s = 0.f, q = 0.f;
        for (int g = 0; g < 48; ++g) { float2 v = red[g * 16 + tid]; s += v.x; q += v.y; }
        float mu = s * (1.f / 192.f);
        float var = q * (1.f / 192.f) - mu * mu;
        stats0[tid] = make_float2(mu, rsqrtf(var + 1e-5f));
    }
    __syncthreads();
    #pragma unroll
    for (int n = 0; n < 4; ++n) {
        float s = 0.f, q = 0.f;
        #pragma unroll
        for (int r = 0; r < 4; ++r) { s += a1[r][n]; q += a1[r][n] * a1[r][n]; }
        red[jg * 16 + nt * 4 + n] = make_float2(s, q);
    }
    {
        const float4 g = *reinterpret_cast<const float4*>(&gp0[j0]);
        const float4 be = *reinterpret_cast<const float4*>(&bep0[j0]);
        const float gr[4] = { g.x, g.y, g.z, g.w };
        const float br[4] = { be.x, be.y, be.z, be.w };
        #pragma unroll
        for (int n = 0; n < 4; ++n) {
            float2 st = stats0[nt * 4 + n];
            float4 o;
            o.x = fmaxf((a0[0][n] - st.x) * st.y * gr[0] + br[0], 0.f);
            o.y = fmaxf((a0[1][n] - st.x) * st.y * gr[1] + br[1], 0.f);
            o.z = fmaxf((a0[2][n] - st.x) * st.y * gr[2] + br[2], 0.f);
            o.w = fmaxf((a0[3][n] - st.x) * st.y * gr[3] + br[3], 0.f);
            *reinterpret_cast<float4*>(&hp[(size_t)(n0 + nt * 4 + n) * 384 + j0]) = o;
        }
    }
    __syncthreads();
    if (tid < 16) {
        float s = 0.f, q = 0.f;
        for (int g = 0; g < 48; ++g) { float2 v = red[g * 16 + tid]; s += v.x; q += v.y; }
        float mu = s * (1.f / 192.f);
        float var = q * (1.f / 192.f) - mu * mu;
        stats1[tid] = make_float2(mu, rsqrtf(var + 1e-5f));
    }
    __syncthreads();
    {
        const float4 g = *reinterpret_cast<const float4*>(&gp1[j0]);
        const float4 be = *reinterpret_cast<const float4*>(&bep1[j0]);
        const float gr[4] = { g.x, g.y, g.z, g.w };
        const float br[4] = { be.x, be.y, be.z, be.w };
        #pragma unroll
        for (int n = 0; n < 4; ++n) {
            float2 st = stats1[nt * 4 + n];
            float4 o;
            o.x = fmaxf((a1[0][n] - st.x) * st.y * gr[0] + br[0], 0.f);
            o.y = fmaxf((a1[1][n] - st.x) * st.y * gr[1] + br[1], 0.f);
            o.z = fmaxf((a1[2][n] - st.x) * st.y * gr[2] + br[2], 0.f);
            o.w = fmaxf((a1[3][n] - st.x) * st.y * gr[3] + br[3], 0.f);
            *reinterpret_cast<float4*>(&hp[(size_t)(n0 + nt * 4 + n) * 384 + 192 + j0]) = o;
        }
    }
}

// ---------------------------------------------------------------------------
// Kernel B: edge scatter (unchanged).
// ---------------------------------------------------------------------------
__global__ __launch_bounds__(256) void k_scatter(
    const float* __restrict__ hp,
    const int* __restrict__ src, const int* __restrict__ dst,
    const int* __restrict__ pos, const float* __restrict__ dist,
    float* __restrict__ acc)
{
    int gid = blockIdx.x * 256 + threadIdx.x;   // NE*96 total
    int e  = gid / 96;
    int f4 = (gid - e * 96) * 4;
    int p = pos[e];
    if (p >= 3) return;
    float w = dist[e];
    int s = src[e], d = dst[e];
    const float4 v = *reinterpret_cast<const float4*>(&hp[(size_t)s * 384 + f4]);
    float* o = &acc[(size_t)d * 1152 + (size_t)p * 384 + f4];
    atomicAdd(o + 0, v.x * w);
    atomicAdd(o + 1, v.y * w);
    atomicAdd(o + 2, v.z * w);
    atomicAdd(o + 3, v.w * w);
}

// ---------------------------------------------------------------------------
// Kernel C: hg = relu(LN(hc @ Wg + bg)), hc = [hp, r, b, l, r] (K=1920).
// 32 nodes/block (1250 blocks), 256 threads: jg = tid&63 owns j = jg*6..+5
// (Jr=6), nt = tid>>6 owns nodes nt*8..+7 (Nr=8).  K in 5 phases of 384,
// each phase maps exactly to one source region (hp | acc r | b | l | r).
// Per k per thread: 2 broadcast ds_read_b128 + 3 float2 W + 48 FMA.
// Wg L2 traffic: 1250 blocks x ~2.95MB (nt-dups are L1 hits) ~ 4 GB.
// hg MAY ALIAS hp: all hp reads happen in phase-0 staging (before barrier);
// hg writes happen after the full K loop.  Blocks touch disjoint rows.
// ---------------------------------------------------------------------------
__global__ __launch_bounds__(256, 4) void k_gemm_hg(
    const float* __restrict__ hp, const float* __restrict__ acc,
    const float* __restrict__ Wg, const float* __restrict__ bg,
    const float* __restrict__ gg, const float* __restrict__ beg,
    float* __restrict__ hg)
{
    __shared__ __align__(16) float xs[384 * 32];    // [c][n], 48 KB
    __shared__ float2 stats[32];
    const int tid = threadIdx.x;
    const int n0  = blockIdx.x * 32;
    const int jg  = tid & 63;           // 64 groups * 6 j = 384
    const int nt  = tid >> 6;           // 4 groups * 8 nodes = 32
    const int j0  = jg * 6;
    const int nb  = nt * 8;
    const int ns  = tid & 31;           // staging: fixed node per thread

    float a[6][8];
    #pragma unroll
    for (int r = 0; r < 6; ++r)
        #pragma unroll
        for (int n = 0; n < 8; ++n) a[r][n] = 0.f;

    for (int t = 0; t < 5; ++t) {
        // ---- stage one 384-column region for 32 nodes ----
        const float* srow;
        if (t == 0)      srow = hp  + (size_t)(n0 + ns) * 384;
        else if (t < 4)  srow = acc + (size_t)(n0 + ns) * 1152 + (size_t)(t - 1) * 384;
        else             srow = acc + (size_t)(n0 + ns) * 1152;           // t = r
        for (int c = tid >> 5; c < 384; c += 8)
            xs[c * 32 + ns] = srow[c];
        __syncthreads();

        const float* wp = Wg + (size_t)t * 384 * 384 + j0;
        for (int kl = 0; kl < 384; ++kl) {
            const float2 w0 = *reinterpret_cast<const float2*>(wp + 0);
            const float2 w1 = *reinterpret_cast<const float2*>(wp + 2);
            const float2 w2 = *reinterpret_cast<const float2*>(wp + 4);
            wp += 384;
            const float4 x0 = *reinterpret_cast<const float4*>(&xs[kl * 32 + nb + 0]);
            const float4 x1 = *reinterpret_cast<const float4*>(&xs[kl * 32 + nb + 4]);
            const float wr[6] = { w0.x, w0.y, w1.x, w1.y, w2.x, w2.y };
            const float xr[8] = { x0.x, x0.y, x0.z, x0.w, x1.x, x1.y, x1.z, x1.w };
            #pragma unroll
            for (int r = 0; r < 6; ++r)
                #pragma unroll
                for (int n = 0; n < 8; ++n) a[r][n] += wr[r] * xr[n];
        }
        __syncthreads();
    }
    // bias
    #pragma unroll
    for (int r = 0; r < 6; ++r) {
        float b = bg[j0 + r];
        #pragma unroll
        for (int n = 0; n < 8; ++n) a[r][n] += b;
    }
    // LN partials via overlay on xs (dead after last compute barrier)
    float2* red = (float2*)xs;          // [jg][32 n] = 16 KB
    #pragma unroll
    for (int n = 0; n < 8; ++n) {
        float s = 0.f, q = 0.f;
        #pragma unroll
        for (int r = 0; r < 6; ++r) { s += a[r][n]; q += a[r][n] * a[r][n]; }
        red[jg * 32 + nb + n] = make_float2(s, q);
    }
    __syncthreads();
    if (tid < 32) {
        float s = 0.f, q = 0.f;
        for (int g = 0; g < 64; ++g) { float2 v = red[g * 32 + tid]; s += v.x; q += v.y; }
        float mu = s * (1.f / 384.f);
        float var = q * (1.f / 384.f) - mu * mu;
        stats[tid] = make_float2(mu, rsqrtf(var + 1e-5f));
    }
    __syncthreads();
    #pragma unroll
    for (int n = 0; n < 8; ++n) {
        float2 st = stats[nb + n];
        float* orow = &hg[(size_t)(n0 + nb + n) * 384 + j0];
        #pragma unroll
        for (int r = 0; r < 6; ++r) {
            float v = (a[r][n] - st.x) * st.y * gg[j0 + r] + beg[j0 + r];
            orow[r] = fmaxf(v, 0.f);
        }
    }
}

// ---------------------------------------------------------------------------
// Kernel D: n = LN(hg @ Wn + bn); cls = softmax(n).  1 wave / node.
// ---------------------------------------------------------------------------
__global__ __launch_bounds__(256) void k_node_head(
    const float* __restrict__ hg,
    const float* __restrict__ Wn, const float* __restrict__ bn,
    const float* __restrict__ gn, const float* __restrict__ ben,
    float* __restrict__ nout, float* __restrict__ cls)
{
    __shared__ float wns[384 * 5];
    const int tid = threadIdx.x;
    for (int i = tid; i < 1920; i += 256) wns[i] = Wn[i];
    __syncthreads();
    const int wid = tid >> 6, lane = tid & 63;
    const int node = blockIdx.x * 4 + wid;
    float a0 = 0, a1 = 0, a2 = 0, a3 = 0, a4 = 0;
    const float* row = hg + (size_t)node * 384;
    for (int k = lane; k < 384; k += 64) {
        float v = row[k];
        const float* wp = &wns[k * 5];
        a0 += v * wp[0]; a1 += v * wp[1]; a2 += v * wp[2];
        a3 += v * wp[3]; a4 += v * wp[4];
    }
    for (int o = 32; o > 0; o >>= 1) {
        a0 += __shfl_down(a0, o); a1 += __shfl_down(a1, o);
        a2 += __shfl_down(a2, o); a3 += __shfl_down(a3, o);
        a4 += __shfl_down(a4, o);
    }
    if (lane == 0) {
        float v[5] = { a0 + bn[0], a1 + bn[1], a2 + bn[2], a3 + bn[3], a4 + bn[4] };
        float mu = (v[0] + v[1] + v[2] + v[3] + v[4]) * 0.2f;
        float var = 0.0f;
        #pragma unroll
        for (int c = 0; c < 5; ++c) { float d = v[c] - mu; var += d * d; }
        var *= 0.2f;
        float rs = rsqrtf(var + 1e-5f);
        float nv[5]; float m = -1e30f;
        #pragma unroll
        for (int c = 0; c < 5; ++c) {
            nv[c] = (v[c] - mu) * rs * gn[c] + ben[c];
            m = fmaxf(m, nv[c]);
        }
        #pragma unroll
        for (int c = 0; c < 5; ++c) nout[(size_t)node * 5 + c] = nv[c];
        float ex[5]; float s = 0.0f;
        #pragma unroll
        for (int c = 0; c < 5; ++c) { ex[c] = expf(nv[c] - m); s += ex[c]; }
        float inv = 1.0f / s;
        #pragma unroll
        for (int c = 0; c < 5; ++c) cls[(size_t)node * 5 + c] = ex[c] * inv;
    }
}

// ---------------------------------------------------------------------------
// Kernel E: edge MLP, big edge tile.
// 64 edges/block (4000 blocks), 320 threads: jg = tid%80 owns j = jg*4..+3
// (Jr=4, active jg<75), et = tid/80 owns edges et*16..+15 (Er=16).
// K in 4 phases of 196 (xs = 196x64 = 50 KB, 3 blocks/CU).
// Per k per thread: 1 W float4 + 4 broadcast ds_read_b128 + 64 FMA
// -> FMA 128 cyc vs mem ~40 cyc: VALU-bound.
// W1 L2 traffic: 4000 blocks x 0.94MB (et-dups are L1 hits) ~ 4 GB
// (was 60 GB in R4 -- the actual R4 limiter).
// ---------------------------------------------------------------------------
__global__ __launch_bounds__(320, 4) void k_edge_mlp(
    const float* __restrict__ hg, const float* __restrict__ cls,
    const int* __restrict__ srcI, const int* __restrict__ dstI,
    const float* __restrict__ polar,
    const float* __restrict__ W1, const float* __restrict__ b1,
    const float* __restrict__ g1, const float* __restrict__ be1,
    const float* __restrict__ W2, const float* __restrict__ b2,
    float* __restrict__ eout)
{
    __shared__ __align__(16) float xs[196 * 64];   // [cl][e], 50.2 KB
    __shared__ float2 stats[64];
    const int tid = threadIdx.x;
    const int e0  = blockIdx.x * 64;
    const int et  = tid / 80;            // 4 groups x 16 edges
    const int jg  = tid % 80;            // 80 j-groups, 75 active
    const bool act = (jg < 75);
    const int j0  = (act ? jg : 74) * 4;
    const int eb  = et * 16;

    // staging identity: each thread stages one fixed edge column
    const int es  = tid & 63;
    const int eg  = e0 + es;
    const int se  = srcI[eg], de = dstI[eg];

    float a[4][16];                      // [j][e]
    #pragma unroll
    for (int r = 0; r < 4; ++r)
        #pragma unroll
        for (int e = 0; e < 16; ++e) a[r][e] = 0.f;

    for (int t = 0; t < 4; ++t) {
        // ---- stage x[cl][e] for c = t*196 + cl ----
        for (int cl = tid >> 6; cl < 196; cl += 5) {
            int c = t * 196 + cl;
            float v;
            if (c < 384)      v = hg[(size_t)se * 384 + c];
            else if (c < 389) v = cls[(size_t)se * 5 + (c - 384)];
            else if (c < 395) v = polar[(size_t)eg * 6 + (c - 389)];
            else if (c < 779) v = hg[(size_t)de * 384 + (c - 395)];
            else              v = cls[(size_t)de * 5 + (c - 779)];
            xs[cl * 64 + es] = v;
        }
        __syncthreads();

        const float* wp = W1 + (size_t)t * 196 * 300 + j0;
        for (int kl = 0; kl < 196; ++kl) {
            const float4 w = *reinterpret_cast<const float4*>(wp);
            wp += 300;
            const float4 x0 = *reinterpret_cast<const float4*>(&xs[kl * 64 + eb + 0]);
            const float4 x1 = *reinterpret_cast<const float4*>(&xs[kl * 64 + eb + 4]);
            const float4 x2 = *reinterpret_cast<const float4*>(&xs[kl * 64 + eb + 8]);
            const float4 x3 = *reinterpret_cast<const float4*>(&xs[kl * 64 + eb + 12]);
            const float wr[4]  = { w.x, w.y, w.z, w.w };
            const float xr[16] = { x0.x, x0.y, x0.z, x0.w, x1.x, x1.y, x1.z, x1.w,
                                   x2.x, x2.y, x2.z, x2.w, x3.x, x3.y, x3.z, x3.w };
            #pragma unroll
            for (int r = 0; r < 4; ++r)
                #pragma unroll
                for (int e = 0; e < 16; ++e) a[r][e] += wr[r] * xr[e];
        }
        __syncthreads();
    }
    // bias
    {
        const float4 b = *reinterpret_cast<const float4*>(&b1[j0]);
        const float br[4] = { b.x, b.y, b.z, b.w };
        #pragma unroll
        for (int r = 0; r < 4; ++r)
            #pragma unroll
            for (int e = 0; e < 16; ++e) a[r][e] += br[r];
    }
    // ---- LN stats over 300 j per edge (overlay on dead xs) ----
    float2* red = (float2*)xs;           // [jg][64 e] = 40 KB
    if (act) {
        #pragma unroll
        for (int e = 0; e < 16; ++e) {
            float s = 0.f, q = 0.f;
            #pragma unroll
            for (int r = 0; r < 4; ++r) { s += a[r][e]; q += a[r][e] * a[r][e]; }
            red[jg * 64 + eb + e] = make_float2(s, q);
        }
    }
    __syncthreads();
    if (tid < 64) {
        float s = 0.f, q = 0.f;
        for (int g = 0; g < 75; ++g) { float2 v = red[g * 64 + tid]; s += v.x; q += v.y; }
        float mu = s * (1.f / 300.f);
        float var = q * (1.f / 300.f) - mu * mu;
        stats[tid] = make_float2(mu, rsqrtf(var + 1e-5f));
    }
    __syncthreads();

    // ---- LN + relu + layer-2 partials ----
    const float4 g4  = *reinterpret_cast<const float4*>(&g1[j0]);
    const float4 be4 = *reinterpret_cast<const float4*>(&be1[j0]);
    const float4 w2a = *reinterpret_cast<const float4*>(&W2[j0 * 2]);
    const float4 w2b = *reinterpret_cast<const float4*>(&W2[j0 * 2 + 4]);
    const float gr[4]  = { g4.x, g4.y, g4.z, g4.w };
    const float br[4]  = { be4.x, be4.y, be4.z, be4.w };
    const float w20[4] = { w2a.x, w2a.z, w2b.x, w2b.z };
    const float w21[4] = { w2a.y, w2a.w, w2b.y, w2b.w };
    float o0[16], o1[16];
    #pragma unroll
    for (int e = 0; e < 16; ++e) {
        float2 st = stats[eb + e];
        float s0 = 0.f, s1 = 0.f;
        #pragma unroll
        for (int r = 0; r < 4; ++r) {
            float y = fmaxf((a[r][e] - st.x) * st.y * gr[r] + br[r], 0.f);
            s0 += y * w20[r];
            s1 += y * w21[r];
        }
        o0[e] = s0; o1[e] = s1;
    }
    if (act) {
        #pragma unroll
        for (int e = 0; e < 16; ++e)
            red[jg * 64 + eb + e] = make_float2(o0[e], o1[e]);
    }
    __syncthreads();
    if (tid < 128) {
        int e = tid >> 1, c = tid & 1;
        float s = 0.f;
        for (int g = 0; g < 75; ++g) {
            float2 v = red[g * 64 + e];
            s += (c == 0) ? v.x : v.y;
        }
        eout[(size_t)(e0 + e) * 2 + c] = s + b2[c];
    }
}

// ---------------------------------------------------------------------------
extern "C" void kernel_launch(void* const* d_in, const int* in_sizes, int n_in,
                              void* d_out, int out_size, void* d_ws, size_t ws_size,
                              hipStream_t stream)
{
    const float* h     = (const float*)d_in[0];
    const int*   src   = (const int*)d_in[1];
    const int*   dst   = (const int*)d_in[2];
    const int*   pos   = (const int*)d_in[3];
    const float* dist  = (const float*)d_in[4];
    const float* polar = (const float*)d_in[5];
    const float* Wp0   = (const float*)d_in[6];
    const float* bp0   = (const float*)d_in[7];
    const float* gp0   = (const float*)d_in[8];
    const float* bep0  = (const float*)d_in[9];
    const float* Wp1   = (const float*)d_in[10];
    const float* bp1   = (const float*)d_in[11];
    const float* gp1   = (const float*)d_in[12];
    const float* bep1  = (const float*)d_in[13];
    const float* Wg    = (const float*)d_in[14];
    const float* bg    = (const float*)d_in[15];
    const float* gg    = (const float*)d_in[16];
    const float* beg   = (const float*)d_in[17];
    const float* Wn    = (const float*)d_in[18];
    const float* bn    = (const float*)d_in[19];
    const float* gn    = (const float*)d_in[20];
    const float* ben   = (const float*)d_in[21];
    const float* W1    = (const float*)d_in[22];
    const float* b1    = (const float*)d_in[23];
    const float* g1    = (const float*)d_in[24];
    const float* be1   = (const float*)d_in[25];
    const float* W2    = (const float*)d_in[26];
    const float* b2    = (const float*)d_in[27];

    float* ws  = (float*)d_ws;
    float* acc = ws + ACC_OFF;
    float* hp  = ws + HP_OFF;
    float* hg  = hp;                        // aliased (see k_gemm_hg comment)
    float* cls = ws + CLS_OFF;
    float* nout = (float*)d_out;            // 40000*5
    float* eout = (float*)d_out + 200000;   // 256000*2

    k_zero<<<2048, 256, 0, stream>>>((float4*)acc, ACC_FLOATS / 4);

    k_proj<<<2500, 192, 0, stream>>>(h, Wp0, bp0, gp0, bep0,
                                     Wp1, bp1, gp1, bep1, hp);
    k_scatter<<<96000, 256, 0, stream>>>(hp, src, dst, pos, dist, acc);
    k_gemm_hg<<<1250, 256, 0, stream>>>(hp, acc, Wg, bg, gg, beg, hg);
    k_node_head<<<10000, 256, 0, stream>>>(hg, Wn, bn, gn, ben, nout, cls);
    k_edge_mlp<<<4000, 320, 0, stream>>>(hg, cls, src, dst, polar,
                                         W1, b1, g1, be1, W2, b2, eout);
}

// Round 6
// 4653.950 us; speedup vs baseline: 1.8298x; 1.1794x over previous
//
#include <hip/hip_runtime.h>
#include <math.h>

// Problem constants
#define NN 40000
#define NE 256000

// Workspace layout (floats), total 61,640,000 floats = 246.6 MB
//  acc : 40000*1152 = 46,080,000   [r|b|l] scatter accumulators
//  hp  : 40000*384  = 15,360,000   projected node features; REUSED as hg
//  cls : 40000*5    =    200,000   softmax probs
static const size_t ACC_OFF = 0;
static const size_t HP_OFF  = 46080000;
static const size_t CLS_OFF = 61440000;
#define ACC_FLOATS 46080000

// ---------------------------------------------------------------------------
__global__ __launch_bounds__(256) void k_zero(float4* __restrict__ p, int n4)
{
    int stride = gridDim.x * 256;
    for (int i = blockIdx.x * 256 + threadIdx.x; i < n4; i += stride)
        p[i] = make_float4(0.f, 0.f, 0.f, 0.f);
}

// ---------------------------------------------------------------------------
// Kernel A: fused projections, register-blocked (unchanged from R4/R5).
// ---------------------------------------------------------------------------
__global__ __launch_bounds__(192) void k_proj(
    const float* __restrict__ h,
    const float* __restrict__ Wp0, const float* __restrict__ bp0,
    const float* __restrict__ gp0, const float* __restrict__ bep0,
    const float* __restrict__ Wp1, const float* __restrict__ bp1,
    const float* __restrict__ gp1, const float* __restrict__ bep1,
    float* __restrict__ hp)
{
    __shared__ __align__(16) float xs[384 * 16];   // [c][n], 24.6 KB
    __shared__ float2 stats0[16], stats1[16];
    const int tid = threadIdx.x;
    const int n0  = blockIdx.x * 16;
    const int jg  = tid % 48;
    const int nt  = tid / 48;
    const int j0  = jg * 4;

    for (int idx = tid; idx < 384 * 16; idx += 192) {
        int n = idx & 15, c = idx >> 4;
        xs[c * 16 + n] = h[(size_t)(n0 + n) * 384 + c];
    }
    __syncthreads();

    float a0[4][4], a1[4][4];
    #pragma unroll
    for (int r = 0; r < 4; ++r)
        #pragma unroll
        for (int n = 0; n < 4; ++n) { a0[r][n] = 0.f; a1[r][n] = 0.f; }

    #pragma unroll 2
    for (int k = 0; k < 300; ++k) {
        const float4 x = *reinterpret_cast<const float4*>(&xs[k * 16 + nt * 4]);
        const float4 w = *reinterpret_cast<const float4*>(&Wp0[k * 192 + j0]);
        const float wr[4] = { w.x, w.y, w.z, w.w };
        const float xr[4] = { x.x, x.y, x.z, x.w };
        #pragma unroll
        for (int r = 0; r < 4; ++r)
            #pragma unroll
            for (int n = 0; n < 4; ++n) a0[r][n] += wr[r] * xr[n];
    }
    #pragma unroll 2
    for (int k = 0; k < 84; ++k) {
        const float4 x = *reinterpret_cast<const float4*>(&xs[(300 + k) * 16 + nt * 4]);
        const float4 w = *reinterpret_cast<const float4*>(&Wp1[k * 192 + j0]);
        const float wr[4] = { w.x, w.y, w.z, w.w };
        const float xr[4] = { x.x, x.y, x.z, x.w };
        #pragma unroll
        for (int r = 0; r < 4; ++r)
            #pragma unroll
            for (int n = 0; n < 4; ++n) a1[r][n] += wr[r] * xr[n];
    }
    {
        const float4 b0 = *reinterpret_cast<const float4*>(&bp0[j0]);
        const float4 b1 = *reinterpret_cast<const float4*>(&bp1[j0]);
        const float b0r[4] = { b0.x, b0.y, b0.z, b0.w };
        const float b1r[4] = { b1.x, b1.y, b1.z, b1.w };
        #pragma unroll
        for (int r = 0; r < 4; ++r)
            #pragma unroll
            for (int n = 0; n < 4; ++n) { a0[r][n] += b0r[r]; a1[r][n] += b1r[r]; }
    }
    __syncthreads();
    float2* red = (float2*)xs;

    #pragma unroll
    for (int n = 0; n < 4; ++n) {
        float s = 0.f, q = 0.f;
        #pragma unroll
        for (int r = 0; r < 4; ++r) { s += a0[r][n]; q += a0[r][n] * a0[r][n]; }
        red[jg * 16 + nt * 4 + n] = make_float2(s, q);
    }
    __syncthreads();
    if (tid < 16) {
        float s = 0.f, q = 0.f;
        for (int g = 0; g < 48; ++g) { float2 v = red[g * 16 + tid]; s += v.x; q += v.y; }
        float mu = s * (1.f / 192.f);
        float var = q * (1.f / 192.f) - mu * mu;
        stats0[tid] = make_float2(mu, rsqrtf(var + 1e-5f));
    }
    __syncthreads();
    #pragma unroll
    for (int n = 0; n < 4; ++n) {
        float s = 0.f, q = 0.f;
        #pragma unroll
        for (int r = 0; r < 4; ++r) { s += a1[r][n]; q += a1[r][n] * a1[r][n]; }
        red[jg * 16 + nt * 4 + n] = make_float2(s, q);
    }
    {
        const float4 g = *reinterpret_cast<const float4*>(&gp0[j0]);
        const float4 be = *reinterpret_cast<const float4*>(&bep0[j0]);
        const float gr[4] = { g.x, g.y, g.z, g.w };
        const float br[4] = { be.x, be.y, be.z, be.w };
        #pragma unroll
        for (int n = 0; n < 4; ++n) {
            float2 st = stats0[nt * 4 + n];
            float4 o;
            o.x = fmaxf((a0[0][n] - st.x) * st.y * gr[0] + br[0], 0.f);
            o.y = fmaxf((a0[1][n] - st.x) * st.y * gr[1] + br[1], 0.f);
            o.z = fmaxf((a0[2][n] - st.x) * st.y * gr[2] + br[2], 0.f);
            o.w = fmaxf((a0[3][n] - st.x) * st.y * gr[3] + br[3], 0.f);
            *reinterpret_cast<float4*>(&hp[(size_t)(n0 + nt * 4 + n) * 384 + j0]) = o;
        }
    }
    __syncthreads();
    if (tid < 16) {
        float s = 0.f, q = 0.f;
        for (int g = 0; g < 48; ++g) { float2 v = red[g * 16 + tid]; s += v.x; q += v.y; }
        float mu = s * (1.f / 192.f);
        float var = q * (1.f / 192.f) - mu * mu;
        stats1[tid] = make_float2(mu, rsqrtf(var + 1e-5f));
    }
    __syncthreads();
    {
        const float4 g = *reinterpret_cast<const float4*>(&gp1[j0]);
        const float4 be = *reinterpret_cast<const float4*>(&bep1[j0]);
        const float gr[4] = { g.x, g.y, g.z, g.w };
        const float br[4] = { be.x, be.y, be.z, be.w };
        #pragma unroll
        for (int n = 0; n < 4; ++n) {
            float2 st = stats1[nt * 4 + n];
            float4 o;
            o.x = fmaxf((a1[0][n] - st.x) * st.y * gr[0] + br[0], 0.f);
            o.y = fmaxf((a1[1][n] - st.x) * st.y * gr[1] + br[1], 0.f);
            o.z = fmaxf((a1[2][n] - st.x) * st.y * gr[2] + br[2], 0.f);
            o.w = fmaxf((a1[3][n] - st.x) * st.y * gr[3] + br[3], 0.f);
            *reinterpret_cast<float4*>(&hp[(size_t)(n0 + nt * 4 + n) * 384 + 192 + j0]) = o;
        }
    }
}

// ---------------------------------------------------------------------------
// Kernel B: edge scatter (unchanged).
// ---------------------------------------------------------------------------
__global__ __launch_bounds__(256) void k_scatter(
    const float* __restrict__ hp,
    const int* __restrict__ src, const int* __restrict__ dst,
    const int* __restrict__ pos, const float* __restrict__ dist,
    float* __restrict__ acc)
{
    int gid = blockIdx.x * 256 + threadIdx.x;   // NE*96 total
    int e  = gid / 96;
    int f4 = (gid - e * 96) * 4;
    int p = pos[e];
    if (p >= 3) return;
    float w = dist[e];
    int s = src[e], d = dst[e];
    const float4 v = *reinterpret_cast<const float4*>(&hp[(size_t)s * 384 + f4]);
    float* o = &acc[(size_t)d * 1152 + (size_t)p * 384 + f4];
    atomicAdd(o + 0, v.x * w);
    atomicAdd(o + 1, v.y * w);
    atomicAdd(o + 2, v.z * w);
    atomicAdd(o + 3, v.w * w);
}

// ---------------------------------------------------------------------------
// Kernel C: hg = relu(LN(hc @ Wg + bg)), hc = [hp, r, b, l, r] (K=1920).
// 32 nodes/block (1250 blocks), 256 threads.
// jg = tid&31 owns j = jg*12..+11 (Jr=12, 32x12=384, no masking).
// nt = tid>>5 owns nodes nt*4..+3 (Nr=4); half-wave-aligned -> the per-kl
// x float4 read has <=2 distinct addresses per wave (2-way = free).
// Per kl per thread: 1 ds_read_b128 + 3 W float4 + 48 FMA  (FMA:LDS = 48:1).
// LN epilogue fully via __shfl_xor within the 32-lane jg group: no LDS, no
// barriers, no bank conflicts.
// hg MAY ALIAS hp: all hp reads happen in phase-0 staging; writes at end.
// ---------------------------------------------------------------------------
__global__ __launch_bounds__(256) void k_gemm_hg(
    const float* __restrict__ hp, const float* __restrict__ acc,
    const float* __restrict__ Wg, const float* __restrict__ bg,
    const float* __restrict__ gg, const float* __restrict__ beg,
    float* __restrict__ hg)
{
    __shared__ __align__(16) float xs[384 * 32];    // [c][n], 48 KB
    const int tid = threadIdx.x;
    const int n0  = blockIdx.x * 32;
    const int jg  = tid & 31;           // 32 groups * 12 j = 384
    const int nt  = tid >> 5;           // 8 groups * 4 nodes = 32
    const int j0  = jg * 12;
    const int nb  = nt * 4;
    const int ns  = tid & 31;           // staging: fixed node per thread

    float a[12][4];
    #pragma unroll
    for (int r = 0; r < 12; ++r)
        #pragma unroll
        for (int n = 0; n < 4; ++n) a[r][n] = 0.f;

    for (int t = 0; t < 5; ++t) {
        // ---- stage one 384-column region for 32 nodes ----
        const float* srow;
        if (t == 0)      srow = hp  + (size_t)(n0 + ns) * 384;
        else if (t < 4)  srow = acc + (size_t)(n0 + ns) * 1152 + (size_t)(t - 1) * 384;
        else             srow = acc + (size_t)(n0 + ns) * 1152;           // t = r
        for (int c = tid >> 5; c < 384; c += 8)
            xs[c * 32 + ns] = srow[c];
        __syncthreads();

        const float* wp = Wg + (size_t)t * 384 * 384 + j0;
        for (int kl = 0; kl < 384; ++kl) {
            const float4 w0 = *reinterpret_cast<const float4*>(wp + 0);
            const float4 w1 = *reinterpret_cast<const float4*>(wp + 4);
            const float4 w2 = *reinterpret_cast<const float4*>(wp + 8);
            wp += 384;
            const float4 x = *reinterpret_cast<const float4*>(&xs[kl * 32 + nb]);
            const float wr[12] = { w0.x, w0.y, w0.z, w0.w, w1.x, w1.y, w1.z, w1.w,
                                   w2.x, w2.y, w2.z, w2.w };
            const float xr[4]  = { x.x, x.y, x.z, x.w };
            #pragma unroll
            for (int r = 0; r < 12; ++r)
                #pragma unroll
                for (int n = 0; n < 4; ++n) a[r][n] += wr[r] * xr[n];
        }
        __syncthreads();
    }
    // bias
    {
        const float4 b0 = *reinterpret_cast<const float4*>(&bg[j0 + 0]);
        const float4 b1 = *reinterpret_cast<const float4*>(&bg[j0 + 4]);
        const float4 b2 = *reinterpret_cast<const float4*>(&bg[j0 + 8]);
        const float br[12] = { b0.x, b0.y, b0.z, b0.w, b1.x, b1.y, b1.z, b1.w,
                               b2.x, b2.y, b2.z, b2.w };
        #pragma unroll
        for (int r = 0; r < 12; ++r)
            #pragma unroll
            for (int n = 0; n < 4; ++n) a[r][n] += br[r];
    }
    // LN stats via half-wave (32-lane) butterfly: jg spans 0..31 = all 384 j
    const float4 gA = *reinterpret_cast<const float4*>(&gg[j0 + 0]);
    const float4 gB = *reinterpret_cast<const float4*>(&gg[j0 + 4]);
    const float4 gC = *reinterpret_cast<const float4*>(&gg[j0 + 8]);
    const float4 eA = *reinterpret_cast<const float4*>(&beg[j0 + 0]);
    const float4 eB = *reinterpret_cast<const float4*>(&beg[j0 + 4]);
    const float4 eC = *reinterpret_cast<const float4*>(&beg[j0 + 8]);
    const float gr[12] = { gA.x, gA.y, gA.z, gA.w, gB.x, gB.y, gB.z, gB.w,
                           gC.x, gC.y, gC.z, gC.w };
    const float er[12] = { eA.x, eA.y, eA.z, eA.w, eB.x, eB.y, eB.z, eB.w,
                           eC.x, eC.y, eC.z, eC.w };
    #pragma unroll
    for (int n = 0; n < 4; ++n) {
        float s = 0.f, q = 0.f;
        #pragma unroll
        for (int r = 0; r < 12; ++r) { s += a[r][n]; q += a[r][n] * a[r][n]; }
        #pragma unroll
        for (int o = 16; o > 0; o >>= 1) {
            s += __shfl_xor(s, o, 32);
            q += __shfl_xor(q, o, 32);
        }
        float mu = s * (1.f / 384.f);
        float var = q * (1.f / 384.f) - mu * mu;
        float rs = rsqrtf(var + 1e-5f);
        float out[12];
        #pragma unroll
        for (int r = 0; r < 12; ++r)
            out[r] = fmaxf((a[r][n] - mu) * rs * gr[r] + er[r], 0.f);
        float* orow = &hg[(size_t)(n0 + nb + n) * 384 + j0];
        *reinterpret_cast<float4*>(orow + 0) = make_float4(out[0], out[1], out[2], out[3]);
        *reinterpret_cast<float4*>(orow + 4) = make_float4(out[4], out[5], out[6], out[7]);
        *reinterpret_cast<float4*>(orow + 8) = make_float4(out[8], out[9], out[10], out[11]);
    }
}

// ---------------------------------------------------------------------------
// Kernel D: n = LN(hg @ Wn + bn); cls = softmax(n).  1 wave / node.
// ---------------------------------------------------------------------------
__global__ __launch_bounds__(256) void k_node_head(
    const float* __restrict__ hg,
    const float* __restrict__ Wn, const float* __restrict__ bn,
    const float* __restrict__ gn, const float* __restrict__ ben,
    float* __restrict__ nout, float* __restrict__ cls)
{
    __shared__ float wns[384 * 5];
    const int tid = threadIdx.x;
    for (int i = tid; i < 1920; i += 256) wns[i] = Wn[i];
    __syncthreads();
    const int wid = tid >> 6, lane = tid & 63;
    const int node = blockIdx.x * 4 + wid;
    float a0 = 0, a1 = 0, a2 = 0, a3 = 0, a4 = 0;
    const float* row = hg + (size_t)node * 384;
    for (int k = lane; k < 384; k += 64) {
        float v = row[k];
        const float* wp = &wns[k * 5];
        a0 += v * wp[0]; a1 += v * wp[1]; a2 += v * wp[2];
        a3 += v * wp[3]; a4 += v * wp[4];
    }
    for (int o = 32; o > 0; o >>= 1) {
        a0 += __shfl_down(a0, o); a1 += __shfl_down(a1, o);
        a2 += __shfl_down(a2, o); a3 += __shfl_down(a3, o);
        a4 += __shfl_down(a4, o);
    }
    if (lane == 0) {
        float v[5] = { a0 + bn[0], a1 + bn[1], a2 + bn[2], a3 + bn[3], a4 + bn[4] };
        float mu = (v[0] + v[1] + v[2] + v[3] + v[4]) * 0.2f;
        float var = 0.0f;
        #pragma unroll
        for (int c = 0; c < 5; ++c) { float d = v[c] - mu; var += d * d; }
        var *= 0.2f;
        float rs = rsqrtf(var + 1e-5f);
        float nv[5]; float m = -1e30f;
        #pragma unroll
        for (int c = 0; c < 5; ++c) {
            nv[c] = (v[c] - mu) * rs * gn[c] + ben[c];
            m = fmaxf(m, nv[c]);
        }
        #pragma unroll
        for (int c = 0; c < 5; ++c) nout[(size_t)node * 5 + c] = nv[c];
        float ex[5]; float s = 0.0f;
        #pragma unroll
        for (int c = 0; c < 5; ++c) { ex[c] = expf(nv[c] - m); s += ex[c]; }
        float inv = 1.0f / s;
        #pragma unroll
        for (int c = 0; c < 5; ++c) cls[(size_t)node * 5 + c] = ex[c] * inv;
    }
}

// ---------------------------------------------------------------------------
// Kernel E: edge MLP, half-wave structure.
// 64 edges/block (4000 blocks), 256 threads = 8 half-waves.
// Half-wave hw = tid>>5 owns 8 edges (eb = hw*8); within it, jg = tid&31
// owns j = jg*10..+9 (Jr=10; jg<30 active -> 300 j, lanes 30/31 masked).
// Per kl per thread: 2 broadcast ds_read_b128 (<=2 distinct addrs/wave,
// conflict-free) + 5 W float2 + 80 FMA  (FMA:LDS cyc = 160:24 per wave).
// K in 4 phases of 196; xs stride 68 floats (16B-aligned, c-coalesced
// global staging). LN + W2 epilogue entirely in-register via __shfl_xor
// width-32 butterflies -- no LDS epilogue, no extra barriers.
// ---------------------------------------------------------------------------
#define EM_KC 196
#define EM_ST 68

__global__ __launch_bounds__(256, 2) void k_edge_mlp(
    const float* __restrict__ hg, const float* __restrict__ cls,
    const int* __restrict__ srcI, const int* __restrict__ dstI,
    const float* __restrict__ polar,
    const float* __restrict__ W1, const float* __restrict__ b1,
    const float* __restrict__ g1, const float* __restrict__ be1,
    const float* __restrict__ W2, const float* __restrict__ b2,
    float* __restrict__ eout)
{
    __shared__ __align__(16) float xs[EM_KC * EM_ST];   // [cl][e], 53.3 KB
    const int tid = threadIdx.x;
    const int e0  = blockIdx.x * 64;
    const int hw  = tid >> 5;            // half-wave id, 0..7
    const int jg  = tid & 31;            // 0..31, active jg<30
    const bool act = (jg < 30);
    const float actf = act ? 1.f : 0.f;
    const int j0  = (act ? jg : 29) * 10;
    const int eb  = hw * 8;

    float a[10][8];                      // [j][e]
    #pragma unroll
    for (int r = 0; r < 10; ++r)
        #pragma unroll
        for (int e = 0; e < 8; ++e) a[r][e] = 0.f;

    for (int t = 0; t < 4; ++t) {
        // ---- stage: per edge, lanes = consecutive c (coalesced global) ----
        if (tid < EM_KC) {
            const int c = t * EM_KC + tid;
            for (int e = 0; e < 64; ++e) {
                const int eg = e0 + e;
                float v;
                if (c < 384)      v = hg[(size_t)srcI[eg] * 384 + c];
                else if (c < 389) v = cls[(size_t)srcI[eg] * 5 + (c - 384)];
                else if (c < 395) v = polar[(size_t)eg * 6 + (c - 389)];
                else if (c < 779) v = hg[(size_t)dstI[eg] * 384 + (c - 395)];
                else              v = cls[(size_t)dstI[eg] * 5 + (c - 779)];
                xs[tid * EM_ST + e] = v;
            }
        }
        __syncthreads();

        const float* wp = W1 + (size_t)t * EM_KC * 300 + j0;
        for (int kl = 0; kl < EM_KC; ++kl) {
            const float2 wA = *reinterpret_cast<const float2*>(wp + 0);
            const float2 wB = *reinterpret_cast<const float2*>(wp + 2);
            const float2 wC = *reinterpret_cast<const float2*>(wp + 4);
            const float2 wD = *reinterpret_cast<const float2*>(wp + 6);
            const float2 wE = *reinterpret_cast<const float2*>(wp + 8);
            wp += 300;
            const float4 xa = *reinterpret_cast<const float4*>(&xs[kl * EM_ST + eb + 0]);
            const float4 xb = *reinterpret_cast<const float4*>(&xs[kl * EM_ST + eb + 4]);
            const float wr[10] = { wA.x, wA.y, wB.x, wB.y, wC.x, wC.y,
                                   wD.x, wD.y, wE.x, wE.y };
            const float xr[8]  = { xa.x, xa.y, xa.z, xa.w, xb.x, xb.y, xb.z, xb.w };
            #pragma unroll
            for (int r = 0; r < 10; ++r)
                #pragma unroll
                for (int e = 0; e < 8; ++e) a[r][e] += wr[r] * xr[e];
        }
        __syncthreads();
    }

    // ---- bias ----
    {
        const float2 bA = *reinterpret_cast<const float2*>(&b1[j0 + 0]);
        const float2 bB = *reinterpret_cast<const float2*>(&b1[j0 + 2]);
        const float2 bC = *reinterpret_cast<const float2*>(&b1[j0 + 4]);
        const float2 bD = *reinterpret_cast<const float2*>(&b1[j0 + 6]);
        const float2 bE = *reinterpret_cast<const float2*>(&b1[j0 + 8]);
        const float br[10] = { bA.x, bA.y, bB.x, bB.y, bC.x, bC.y,
                               bD.x, bD.y, bE.x, bE.y };
        #pragma unroll
        for (int r = 0; r < 10; ++r)
            #pragma unroll
            for (int e = 0; e < 8; ++e) a[r][e] += br[r];
    }

    // ---- LN stats: butterfly over the 32-lane jg dimension ----
    float mu[8], rs[8];
    #pragma unroll
    for (int e = 0; e < 8; ++e) {
        float s = 0.f, q = 0.f;
        #pragma unroll
        for (int r = 0; r < 10; ++r) { s += a[r][e]; q += a[r][e] * a[r][e]; }
        s *= actf; q *= actf;
        #pragma unroll
        for (int o = 16; o > 0; o >>= 1) {
            s += __shfl_xor(s, o, 32);
            q += __shfl_xor(q, o, 32);
        }
        mu[e] = s * (1.f / 300.f);
        float var = q * (1.f / 300.f) - mu[e] * mu[e];
        rs[e] = rsqrtf(var + 1e-5f);
    }

    // ---- LN + relu + layer-2 partials + butterfly reduce ----
    const float2 gA = *reinterpret_cast<const float2*>(&g1[j0 + 0]);
    const float2 gB = *reinterpret_cast<const float2*>(&g1[j0 + 2]);
    const float2 gC = *reinterpret_cast<const float2*>(&g1[j0 + 4]);
    const float2 gD = *reinterpret_cast<const float2*>(&g1[j0 + 6]);
    const float2 gE = *reinterpret_cast<const float2*>(&g1[j0 + 8]);
    const float2 eA = *reinterpret_cast<const float2*>(&be1[j0 + 0]);
    const float2 eB = *reinterpret_cast<const float2*>(&be1[j0 + 2]);
    const float2 eC = *reinterpret_cast<const float2*>(&be1[j0 + 4]);
    const float2 eD = *reinterpret_cast<const float2*>(&be1[j0 + 6]);
    const float2 eE = *reinterpret_cast<const float2*>(&be1[j0 + 8]);
    const float gr[10] = { gA.x, gA.y, gB.x, gB.y, gC.x, gC.y, gD.x, gD.y, gE.x, gE.y };
    const float er[10] = { eA.x, eA.y, eB.x, eB.y, eC.x, eC.y, eD.x, eD.y, eE.x, eE.y };
    float w20[10], w21[10];
    #pragma unroll
    for (int r = 0; r < 10; ++r) {
        const float2 w2 = *reinterpret_cast<const float2*>(&W2[(j0 + r) * 2]);
        w20[r] = w2.x; w21[r] = w2.y;
    }
    float o0[8], o1[8];
    #pragma unroll
    for (int e = 0; e < 8; ++e) {
        float s0 = 0.f, s1 = 0.f;
        #pragma unroll
        for (int r = 0; r < 10; ++r) {
            float y = fmaxf((a[r][e] - mu[e]) * rs[e] * gr[r] + er[r], 0.f);
            s0 += y * w20[r];
            s1 += y * w21[r];
        }
        s0 *= actf; s1 *= actf;
        #pragma unroll
        for (int o = 16; o > 0; o >>= 1) {
            s0 += __shfl_xor(s0, o, 32);
            s1 += __shfl_xor(s1, o, 32);
        }
        o0[e] = s0; o1[e] = s1;
    }
    if (jg == 0) {
        const float b20 = b2[0], b21 = b2[1];
        #pragma unroll
        for (int e = 0; e < 8; ++e)
            *reinterpret_cast<float2*>(&eout[(size_t)(e0 + eb + e) * 2]) =
                make_float2(o0[e] + b20, o1[e] + b21);
    }
}

// ---------------------------------------------------------------------------
extern "C" void kernel_launch(void* const* d_in, const int* in_sizes, int n_in,
                              void* d_out, int out_size, void* d_ws, size_t ws_size,
                              hipStream_t stream)
{
    const float* h     = (const float*)d_in[0];
    const int*   src   = (const int*)d_in[1];
    const int*   dst   = (const int*)d_in[2];
    const int*   pos   = (const int*)d_in[3];
    const float* dist  = (const float*)d_in[4];
    const float* polar = (const float*)d_in[5];
    const float* Wp0   = (const float*)d_in[6];
    const float* bp0   = (const float*)d_in[7];
    const float* gp0   = (const float*)d_in[8];
    const float* bep0  = (const float*)d_in[9];
    const float* Wp1   = (const float*)d_in[10];
    const float* bp1   = (const float*)d_in[11];
    const float* gp1   = (const float*)d_in[12];
    const float* bep1  = (const float*)d_in[13];
    const float* Wg    = (const float*)d_in[14];
    const float* bg    = (const float*)d_in[15];
    const float* gg    = (const float*)d_in[16];
    const float* beg   = (const float*)d_in[17];
    const float* Wn    = (const float*)d_in[18];
    const float* bn    = (const float*)d_in[19];
    const float* gn    = (const float*)d_in[20];
    const float* ben   = (const float*)d_in[21];
    const float* W1    = (const float*)d_in[22];
    const float* b1    = (const float*)d_in[23];
    const float* g1    = (const float*)d_in[24];
    const float* be1   = (const float*)d_in[25];
    const float* W2    = (const float*)d_in[26];
    const float* b2    = (const float*)d_in[27];

    float* ws  = (float*)d_ws;
    float* acc = ws + ACC_OFF;
    float* hp  = ws + HP_OFF;
    float* hg  = hp;                        // aliased (see k_gemm_hg comment)
    float* cls = ws + CLS_OFF;
    float* nout = (float*)d_out;            // 40000*5
    float* eout = (float*)d_out + 200000;   // 256000*2

    k_zero<<<2048, 256, 0, stream>>>((float4*)acc, ACC_FLOATS / 4);

    k_proj<<<2500, 192, 0, stream>>>(h, Wp0, bp0, gp0, bep0,
                                     Wp1, bp1, gp1, bep1, hp);
    k_scatter<<<96000, 256, 0, stream>>>(hp, src, dst, pos, dist, acc);
    k_gemm_hg<<<1250, 256, 0, stream>>>(hp, acc, Wg, bg, gg, beg, hg);
    k_node_head<<<10000, 256, 0, stream>>>(hg, Wn, bn, gn, ben, nout, cls);
    k_edge_mlp<<<4000, 256, 0, stream>>>(hg, cls, src, dst, polar,
                                         W1, b1, g1, be1, W2, b2, eout);
}

// Round 7
// 4622.677 us; speedup vs baseline: 1.8421x; 1.0068x over previous
//
#include <hip/hip_runtime.h>
#include <math.h>

// Problem constants
#define NN 40000
#define NE 256000

// Workspace layout (floats), total 61,640,000 floats = 246.6 MB
//  acc : 40000*1152 = 46,080,000   [r|b|l] scatter accumulators
//  hp  : 40000*384  = 15,360,000   projected node features; REUSED as hg
//  cls : 40000*5    =    200,000   softmax probs
static const size_t ACC_OFF = 0;
static const size_t HP_OFF  = 46080000;
static const size_t CLS_OFF = 61440000;
#define ACC_FLOATS 46080000

// ---------------------------------------------------------------------------
__global__ __launch_bounds__(256) void k_zero(float4* __restrict__ p, int n4)
{
    int stride = gridDim.x * 256;
    for (int i = blockIdx.x * 256 + threadIdx.x; i < n4; i += stride)
        p[i] = make_float4(0.f, 0.f, 0.f, 0.f);
}

// ---------------------------------------------------------------------------
// Kernel A: fused projections, register-blocked (unchanged).
// ---------------------------------------------------------------------------
__global__ __launch_bounds__(192) void k_proj(
    const float* __restrict__ h,
    const float* __restrict__ Wp0, const float* __restrict__ bp0,
    const float* __restrict__ gp0, const float* __restrict__ bep0,
    const float* __restrict__ Wp1, const float* __restrict__ bp1,
    const float* __restrict__ gp1, const float* __restrict__ bep1,
    float* __restrict__ hp)
{
    __shared__ __align__(16) float xs[384 * 16];   // [c][n], 24.6 KB
    __shared__ float2 stats0[16], stats1[16];
    const int tid = threadIdx.x;
    const int n0  = blockIdx.x * 16;
    const int jg  = tid % 48;
    const int nt  = tid / 48;
    const int j0  = jg * 4;

    for (int idx = tid; idx < 384 * 16; idx += 192) {
        int n = idx & 15, c = idx >> 4;
        xs[c * 16 + n] = h[(size_t)(n0 + n) * 384 + c];
    }
    __syncthreads();

    float a0[4][4], a1[4][4];
    #pragma unroll
    for (int r = 0; r < 4; ++r)
        #pragma unroll
        for (int n = 0; n < 4; ++n) { a0[r][n] = 0.f; a1[r][n] = 0.f; }

    #pragma unroll 2
    for (int k = 0; k < 300; ++k) {
        const float4 x = *reinterpret_cast<const float4*>(&xs[k * 16 + nt * 4]);
        const float4 w = *reinterpret_cast<const float4*>(&Wp0[k * 192 + j0]);
        const float wr[4] = { w.x, w.y, w.z, w.w };
        const float xr[4] = { x.x, x.y, x.z, x.w };
        #pragma unroll
        for (int r = 0; r < 4; ++r)
            #pragma unroll
            for (int n = 0; n < 4; ++n) a0[r][n] += wr[r] * xr[n];
    }
    #pragma unroll 2
    for (int k = 0; k < 84; ++k) {
        const float4 x = *reinterpret_cast<const float4*>(&xs[(300 + k) * 16 + nt * 4]);
        const float4 w = *reinterpret_cast<const float4*>(&Wp1[k * 192 + j0]);
        const float wr[4] = { w.x, w.y, w.z, w.w };
        const float xr[4] = { x.x, x.y, x.z, x.w };
        #pragma unroll
        for (int r = 0; r < 4; ++r)
            #pragma unroll
            for (int n = 0; n < 4; ++n) a1[r][n] += wr[r] * xr[n];
    }
    {
        const float4 b0 = *reinterpret_cast<const float4*>(&bp0[j0]);
        const float4 b1 = *reinterpret_cast<const float4*>(&bp1[j0]);
        const float b0r[4] = { b0.x, b0.y, b0.z, b0.w };
        const float b1r[4] = { b1.x, b1.y, b1.z, b1.w };
        #pragma unroll
        for (int r = 0; r < 4; ++r)
            #pragma unroll
            for (int n = 0; n < 4; ++n) { a0[r][n] += b0r[r]; a1[r][n] += b1r[r]; }
    }
    __syncthreads();
    float2* red = (float2*)xs;

    #pragma unroll
    for (int n = 0; n < 4; ++n) {
        float s = 0.f, q = 0.f;
        #pragma unroll
        for (int r = 0; r < 4; ++r) { s += a0[r][n]; q += a0[r][n] * a0[r][n]; }
        red[jg * 16 + nt * 4 + n] = make_float2(s, q);
    }
    __syncthreads();
    if (tid < 16) {
        float s = 0.f, q = 0.f;
        for (int g = 0; g < 48; ++g) { float2 v = red[g * 16 + tid]; s += v.x; q += v.y; }
        float mu = s * (1.f / 192.f);
        float var = q * (1.f / 192.f) - mu * mu;
        stats0[tid] = make_float2(mu, rsqrtf(var + 1e-5f));
    }
    __syncthreads();
    #pragma unroll
    for (int n = 0; n < 4; ++n) {
        float s = 0.f, q = 0.f;
        #pragma unroll
        for (int r = 0; r < 4; ++r) { s += a1[r][n]; q += a1[r][n] * a1[r][n]; }
        red[jg * 16 + nt * 4 + n] = make_float2(s, q);
    }
    {
        const float4 g = *reinterpret_cast<const float4*>(&gp0[j0]);
        const float4 be = *reinterpret_cast<const float4*>(&bep0[j0]);
        const float gr[4] = { g.x, g.y, g.z, g.w };
        const float br[4] = { be.x, be.y, be.z, be.w };
        #pragma unroll
        for (int n = 0; n < 4; ++n) {
            float2 st = stats0[nt * 4 + n];
            float4 o;
            o.x = fmaxf((a0[0][n] - st.x) * st.y * gr[0] + br[0], 0.f);
            o.y = fmaxf((a0[1][n] - st.x) * st.y * gr[1] + br[1], 0.f);
            o.z = fmaxf((a0[2][n] - st.x) * st.y * gr[2] + br[2], 0.f);
            o.w = fmaxf((a0[3][n] - st.x) * st.y * gr[3] + br[3], 0.f);
            *reinterpret_cast<float4*>(&hp[(size_t)(n0 + nt * 4 + n) * 384 + j0]) = o;
        }
    }
    __syncthreads();
    if (tid < 16) {
        float s = 0.f, q = 0.f;
        for (int g = 0; g < 48; ++g) { float2 v = red[g * 16 + tid]; s += v.x; q += v.y; }
        float mu = s * (1.f / 192.f);
        float var = q * (1.f / 192.f) - mu * mu;
        stats1[tid] = make_float2(mu, rsqrtf(var + 1e-5f));
    }
    __syncthreads();
    {
        const float4 g = *reinterpret_cast<const float4*>(&gp1[j0]);
        const float4 be = *reinterpret_cast<const float4*>(&bep1[j0]);
        const float gr[4] = { g.x, g.y, g.z, g.w };
        const float br[4] = { be.x, be.y, be.z, be.w };
        #pragma unroll
        for (int n = 0; n < 4; ++n) {
            float2 st = stats1[nt * 4 + n];
            float4 o;
            o.x = fmaxf((a1[0][n] - st.x) * st.y * gr[0] + br[0], 0.f);
            o.y = fmaxf((a1[1][n] - st.x) * st.y * gr[1] + br[1], 0.f);
            o.z = fmaxf((a1[2][n] - st.x) * st.y * gr[2] + br[2], 0.f);
            o.w = fmaxf((a1[3][n] - st.x) * st.y * gr[3] + br[3], 0.f);
            *reinterpret_cast<float4*>(&hp[(size_t)(n0 + nt * 4 + n) * 384 + 192 + j0]) = o;
        }
    }
}

// ---------------------------------------------------------------------------
// Kernel B: edge scatter (unchanged).
// ---------------------------------------------------------------------------
__global__ __launch_bounds__(256) void k_scatter(
    const float* __restrict__ hp,
    const int* __restrict__ src, const int* __restrict__ dst,
    const int* __restrict__ pos, const float* __restrict__ dist,
    float* __restrict__ acc)
{
    int gid = blockIdx.x * 256 + threadIdx.x;   // NE*96 total
    int e  = gid / 96;
    int f4 = (gid - e * 96) * 4;
    int p = pos[e];
    if (p >= 3) return;
    float w = dist[e];
    int s = src[e], d = dst[e];
    const float4 v = *reinterpret_cast<const float4*>(&hp[(size_t)s * 384 + f4]);
    float* o = &acc[(size_t)d * 1152 + (size_t)p * 384 + f4];
    atomicAdd(o + 0, v.x * w);
    atomicAdd(o + 1, v.y * w);
    atomicAdd(o + 2, v.z * w);
    atomicAdd(o + 3, v.w * w);
}

// ---------------------------------------------------------------------------
// Kernel C: hg = relu(LN(hc @ Wg + bg)) (unchanged from R6).
// ---------------------------------------------------------------------------
__global__ __launch_bounds__(256) void k_gemm_hg(
    const float* __restrict__ hp, const float* __restrict__ acc,
    const float* __restrict__ Wg, const float* __restrict__ bg,
    const float* __restrict__ gg, const float* __restrict__ beg,
    float* __restrict__ hg)
{
    __shared__ __align__(16) float xs[384 * 32];    // [c][n], 48 KB
    const int tid = threadIdx.x;
    const int n0  = blockIdx.x * 32;
    const int jg  = tid & 31;           // 32 groups * 12 j = 384
    const int nt  = tid >> 5;           // 8 groups * 4 nodes = 32
    const int j0  = jg * 12;
    const int nb  = nt * 4;
    const int ns  = tid & 31;           // staging: fixed node per thread

    float a[12][4];
    #pragma unroll
    for (int r = 0; r < 12; ++r)
        #pragma unroll
        for (int n = 0; n < 4; ++n) a[r][n] = 0.f;

    for (int t = 0; t < 5; ++t) {
        const float* srow;
        if (t == 0)      srow = hp  + (size_t)(n0 + ns) * 384;
        else if (t < 4)  srow = acc + (size_t)(n0 + ns) * 1152 + (size_t)(t - 1) * 384;
        else             srow = acc + (size_t)(n0 + ns) * 1152;           // t = r
        for (int c = tid >> 5; c < 384; c += 8)
            xs[c * 32 + ns] = srow[c];
        __syncthreads();

        const float* wp = Wg + (size_t)t * 384 * 384 + j0;
        for (int kl = 0; kl < 384; ++kl) {
            const float4 w0 = *reinterpret_cast<const float4*>(wp + 0);
            const float4 w1 = *reinterpret_cast<const float4*>(wp + 4);
            const float4 w2 = *reinterpret_cast<const float4*>(wp + 8);
            wp += 384;
            const float4 x = *reinterpret_cast<const float4*>(&xs[kl * 32 + nb]);
            const float wr[12] = { w0.x, w0.y, w0.z, w0.w, w1.x, w1.y, w1.z, w1.w,
                                   w2.x, w2.y, w2.z, w2.w };
            const float xr[4]  = { x.x, x.y, x.z, x.w };
            #pragma unroll
            for (int r = 0; r < 12; ++r)
                #pragma unroll
                for (int n = 0; n < 4; ++n) a[r][n] += wr[r] * xr[n];
        }
        __syncthreads();
    }
    {
        const float4 b0 = *reinterpret_cast<const float4*>(&bg[j0 + 0]);
        const float4 b1 = *reinterpret_cast<const float4*>(&bg[j0 + 4]);
        const float4 b2 = *reinterpret_cast<const float4*>(&bg[j0 + 8]);
        const float br[12] = { b0.x, b0.y, b0.z, b0.w, b1.x, b1.y, b1.z, b1.w,
                               b2.x, b2.y, b2.z, b2.w };
        #pragma unroll
        for (int r = 0; r < 12; ++r)
            #pragma unroll
            for (int n = 0; n < 4; ++n) a[r][n] += br[r];
    }
    const float4 gA = *reinterpret_cast<const float4*>(&gg[j0 + 0]);
    const float4 gB = *reinterpret_cast<const float4*>(&gg[j0 + 4]);
    const float4 gC = *reinterpret_cast<const float4*>(&gg[j0 + 8]);
    const float4 eA = *reinterpret_cast<const float4*>(&beg[j0 + 0]);
    const float4 eB = *reinterpret_cast<const float4*>(&beg[j0 + 4]);
    const float4 eC = *reinterpret_cast<const float4*>(&beg[j0 + 8]);
    const float gr[12] = { gA.x, gA.y, gA.z, gA.w, gB.x, gB.y, gB.z, gB.w,
                           gC.x, gC.y, gC.z, gC.w };
    const float er[12] = { eA.x, eA.y, eA.z, eA.w, eB.x, eB.y, eB.z, eB.w,
                           eC.x, eC.y, eC.z, eC.w };
    #pragma unroll
    for (int n = 0; n < 4; ++n) {
        float s = 0.f, q = 0.f;
        #pragma unroll
        for (int r = 0; r < 12; ++r) { s += a[r][n]; q += a[r][n] * a[r][n]; }
        #pragma unroll
        for (int o = 16; o > 0; o >>= 1) {
            s += __shfl_xor(s, o, 32);
            q += __shfl_xor(q, o, 32);
        }
        float mu = s * (1.f / 384.f);
        float var = q * (1.f / 384.f) - mu * mu;
        float rs = rsqrtf(var + 1e-5f);
        float out[12];
        #pragma unroll
        for (int r = 0; r < 12; ++r)
            out[r] = fmaxf((a[r][n] - mu) * rs * gr[r] + er[r], 0.f);
        float* orow = &hg[(size_t)(n0 + nb + n) * 384 + j0];
        *reinterpret_cast<float4*>(orow + 0) = make_float4(out[0], out[1], out[2], out[3]);
        *reinterpret_cast<float4*>(orow + 4) = make_float4(out[4], out[5], out[6], out[7]);
        *reinterpret_cast<float4*>(orow + 8) = make_float4(out[8], out[9], out[10], out[11]);
    }
}

// ---------------------------------------------------------------------------
// Kernel D: n = LN(hg @ Wn + bn); cls = softmax(n).  1 wave / node.
// ---------------------------------------------------------------------------
__global__ __launch_bounds__(256) void k_node_head(
    const float* __restrict__ hg,
    const float* __restrict__ Wn, const float* __restrict__ bn,
    const float* __restrict__ gn, const float* __restrict__ ben,
    float* __restrict__ nout, float* __restrict__ cls)
{
    __shared__ float wns[384 * 5];
    const int tid = threadIdx.x;
    for (int i = tid; i < 1920; i += 256) wns[i] = Wn[i];
    __syncthreads();
    const int wid = tid >> 6, lane = tid & 63;
    const int node = blockIdx.x * 4 + wid;
    float a0 = 0, a1 = 0, a2 = 0, a3 = 0, a4 = 0;
    const float* row = hg + (size_t)node * 384;
    for (int k = lane; k < 384; k += 64) {
        float v = row[k];
        const float* wp = &wns[k * 5];
        a0 += v * wp[0]; a1 += v * wp[1]; a2 += v * wp[2];
        a3 += v * wp[3]; a4 += v * wp[4];
    }
    for (int o = 32; o > 0; o >>= 1) {
        a0 += __shfl_down(a0, o); a1 += __shfl_down(a1, o);
        a2 += __shfl_down(a2, o); a3 += __shfl_down(a3, o);
        a4 += __shfl_down(a4, o);
    }
    if (lane == 0) {
        float v[5] = { a0 + bn[0], a1 + bn[1], a2 + bn[2], a3 + bn[3], a4 + bn[4] };
        float mu = (v[0] + v[1] + v[2] + v[3] + v[4]) * 0.2f;
        float var = 0.0f;
        #pragma unroll
        for (int c = 0; c < 5; ++c) { float d = v[c] - mu; var += d * d; }
        var *= 0.2f;
        float rs = rsqrtf(var + 1e-5f);
        float nv[5]; float m = -1e30f;
        #pragma unroll
        for (int c = 0; c < 5; ++c) {
            nv[c] = (v[c] - mu) * rs * gn[c] + ben[c];
            m = fmaxf(m, nv[c]);
        }
        #pragma unroll
        for (int c = 0; c < 5; ++c) nout[(size_t)node * 5 + c] = nv[c];
        float ex[5]; float s = 0.0f;
        #pragma unroll
        for (int c = 0; c < 5; ++c) { ex[c] = expf(nv[c] - m); s += ex[c]; }
        float inv = 1.0f / s;
        #pragma unroll
        for (int c = 0; c < 5; ++c) cls[(size_t)node * 5 + c] = ex[c] * inv;
    }
}

// ---------------------------------------------------------------------------
// Kernel E: edge MLP, [e][c] LDS layout + higher occupancy.
// 64 edges/block (4000 blocks), 256 threads = 8 half-waves.
// Half-wave hw = tid>>5 owns 8 edges (eb = hw*8); jg = tid&31 owns
// j = jg*10..+9 (Jr=10; jg<30 active).
// LDS tile xs[e][cl] (stride 116), KC=112, 7 phases, 29.7 KB ->
// __launch_bounds__(256,4) = 4 blocks/CU (2x R6 occupancy).
// Staging: lanes = consecutive c of one edge row -> coalesced global reads
// AND conflict-free LDS writes (this kills R6's 1.8e7 staging conflicts).
// Compute: per 2-kl, 8 broadcast ds_read_b64 (2 distinct addrs/wave = free),
// 10 W float2, 160 FMA.  LN + W2 epilogue in-register via __shfl_xor.
// ---------------------------------------------------------------------------
#define EM_KC 112
#define EM_ST 116

__global__ __launch_bounds__(256, 4) void k_edge_mlp(
    const float* __restrict__ hg, const float* __restrict__ cls,
    const int* __restrict__ srcI, const int* __restrict__ dstI,
    const float* __restrict__ polar,
    const float* __restrict__ W1, const float* __restrict__ b1,
    const float* __restrict__ g1, const float* __restrict__ be1,
    const float* __restrict__ W2, const float* __restrict__ b2,
    float* __restrict__ eout)
{
    __shared__ __align__(16) float xs[64 * EM_ST];   // [e][cl], 29.7 KB
    const int tid = threadIdx.x;
    const int e0  = blockIdx.x * 64;
    const int hw  = tid >> 5;            // half-wave id, 0..7
    const int jg  = tid & 31;            // 0..31, active jg<30
    const bool act = (jg < 30);
    const float actf = act ? 1.f : 0.f;
    const int j0  = (act ? jg : 29) * 10;
    const int eb  = hw * 8;

    // staging identity: 4 e-groups x 64 c-lanes
    const int c_sel = tid & 63;
    const int e_grp = tid >> 6;          // 0..3, 16 edges each

    float a[10][8];                      // [j][e]
    #pragma unroll
    for (int r = 0; r < 10; ++r)
        #pragma unroll
        for (int e = 0; e < 8; ++e) a[r][e] = 0.f;

    for (int t = 0; t < 7; ++t) {
        // ---- stage x[e][cl]: lanes = consecutive c -> coalesced global,
        //      conflict-free LDS writes ----
        for (int eo = 0; eo < 16; ++eo) {
            const int e  = e_grp * 16 + eo;
            const int eg = e0 + e;
            const int se = srcI[eg], de = dstI[eg];
            for (int c = c_sel; c < EM_KC; c += 64) {
                const int cg = t * EM_KC + c;
                float v;
                if (cg < 384)      v = hg[(size_t)se * 384 + cg];
                else if (cg < 389) v = cls[(size_t)se * 5 + (cg - 384)];
                else if (cg < 395) v = polar[(size_t)eg * 6 + (cg - 389)];
                else if (cg < 779) v = hg[(size_t)de * 384 + (cg - 395)];
                else               v = cls[(size_t)de * 5 + (cg - 779)];
                xs[e * EM_ST + c] = v;
            }
        }
        __syncthreads();

        const float* wbase = W1 + (size_t)(t * EM_KC) * 300 + j0;
        for (int kq = 0; kq < EM_KC / 2; ++kq) {
            float2 xv[8];
            #pragma unroll
            for (int i = 0; i < 8; ++i)
                xv[i] = *reinterpret_cast<const float2*>(&xs[(eb + i) * EM_ST + kq * 2]);
            const float* wp = wbase + (size_t)(kq * 2) * 300;
            #pragma unroll
            for (int kk = 0; kk < 2; ++kk) {
                const float2 wA = *reinterpret_cast<const float2*>(wp + kk * 300 + 0);
                const float2 wB = *reinterpret_cast<const float2*>(wp + kk * 300 + 2);
                const float2 wC = *reinterpret_cast<const float2*>(wp + kk * 300 + 4);
                const float2 wD = *reinterpret_cast<const float2*>(wp + kk * 300 + 6);
                const float2 wE = *reinterpret_cast<const float2*>(wp + kk * 300 + 8);
                const float wr[10] = { wA.x, wA.y, wB.x, wB.y, wC.x, wC.y,
                                       wD.x, wD.y, wE.x, wE.y };
                const float xk[8] = {
                    kk ? xv[0].y : xv[0].x, kk ? xv[1].y : xv[1].x,
                    kk ? xv[2].y : xv[2].x, kk ? xv[3].y : xv[3].x,
                    kk ? xv[4].y : xv[4].x, kk ? xv[5].y : xv[5].x,
                    kk ? xv[6].y : xv[6].x, kk ? xv[7].y : xv[7].x };
                #pragma unroll
                for (int r = 0; r < 10; ++r)
                    #pragma unroll
                    for (int e = 0; e < 8; ++e) a[r][e] += wr[r] * xk[e];
            }
        }
        __syncthreads();
    }

    // ---- bias ----
    {
        const float2 bA = *reinterpret_cast<const float2*>(&b1[j0 + 0]);
        const float2 bB = *reinterpret_cast<const float2*>(&b1[j0 + 2]);
        const float2 bC = *reinterpret_cast<const float2*>(&b1[j0 + 4]);
        const float2 bD = *reinterpret_cast<const float2*>(&b1[j0 + 6]);
        const float2 bE = *reinterpret_cast<const float2*>(&b1[j0 + 8]);
        const float br[10] = { bA.x, bA.y, bB.x, bB.y, bC.x, bC.y,
                               bD.x, bD.y, bE.x, bE.y };
        #pragma unroll
        for (int r = 0; r < 10; ++r)
            #pragma unroll
            for (int e = 0; e < 8; ++e) a[r][e] += br[r];
    }

    // ---- LN stats: butterfly over the 32-lane jg dimension ----
    float mu[8], rs[8];
    #pragma unroll
    for (int e = 0; e < 8; ++e) {
        float s = 0.f, q = 0.f;
        #pragma unroll
        for (int r = 0; r < 10; ++r) { s += a[r][e]; q += a[r][e] * a[r][e]; }
        s *= actf; q *= actf;
        #pragma unroll
        for (int o = 16; o > 0; o >>= 1) {
            s += __shfl_xor(s, o, 32);
            q += __shfl_xor(q, o, 32);
        }
        mu[e] = s * (1.f / 300.f);
        float var = q * (1.f / 300.f) - mu[e] * mu[e];
        rs[e] = rsqrtf(var + 1e-5f);
    }

    // ---- LN + relu + layer-2 partials + butterfly reduce ----
    const float2 gA = *reinterpret_cast<const float2*>(&g1[j0 + 0]);
    const float2 gB = *reinterpret_cast<const float2*>(&g1[j0 + 2]);
    const float2 gC = *reinterpret_cast<const float2*>(&g1[j0 + 4]);
    const float2 gD = *reinterpret_cast<const float2*>(&g1[j0 + 6]);
    const float2 gE = *reinterpret_cast<const float2*>(&g1[j0 + 8]);
    const float2 eA = *reinterpret_cast<const float2*>(&be1[j0 + 0]);
    const float2 eB = *reinterpret_cast<const float2*>(&be1[j0 + 2]);
    const float2 eC = *reinterpret_cast<const float2*>(&be1[j0 + 4]);
    const float2 eD = *reinterpret_cast<const float2*>(&be1[j0 + 6]);
    const float2 eE = *reinterpret_cast<const float2*>(&be1[j0 + 8]);
    const float gr[10] = { gA.x, gA.y, gB.x, gB.y, gC.x, gC.y, gD.x, gD.y, gE.x, gE.y };
    const float er[10] = { eA.x, eA.y, eB.x, eB.y, eC.x, eC.y, eD.x, eD.y, eE.x, eE.y };
    float w20[10], w21[10];
    #pragma unroll
    for (int r = 0; r < 10; ++r) {
        const float2 w2 = *reinterpret_cast<const float2*>(&W2[(j0 + r) * 2]);
        w20[r] = w2.x; w21[r] = w2.y;
    }
    float o0[8], o1[8];
    #pragma unroll
    for (int e = 0; e < 8; ++e) {
        float s0 = 0.f, s1 = 0.f;
        #pragma unroll
        for (int r = 0; r < 10; ++r) {
            float y = fmaxf((a[r][e] - mu[e]) * rs[e] * gr[r] + er[r], 0.f);
            s0 += y * w20[r];
            s1 += y * w21[r];
        }
        s0 *= actf; s1 *= actf;
        #pragma unroll
        for (int o = 16; o > 0; o >>= 1) {
            s0 += __shfl_xor(s0, o, 32);
            s1 += __shfl_xor(s1, o, 32);
        }
        o0[e] = s0; o1[e] = s1;
    }
    if (jg == 0) {
        const float b20 = b2[0], b21 = b2[1];
        #pragma unroll
        for (int e = 0; e < 8; ++e)
            *reinterpret_cast<float2*>(&eout[(size_t)(e0 + eb + e) * 2]) =
                make_float2(o0[e] + b20, o1[e] + b21);
    }
}

// ---------------------------------------------------------------------------
extern "C" void kernel_launch(void* const* d_in, const int* in_sizes, int n_in,
                              void* d_out, int out_size, void* d_ws, size_t ws_size,
                              hipStream_t stream)
{
    const float* h     = (const float*)d_in[0];
    const int*   src   = (const int*)d_in[1];
    const int*   dst   = (const int*)d_in[2];
    const int*   pos   = (const int*)d_in[3];
    const float* dist  = (const float*)d_in[4];
    const float* polar = (const float*)d_in[5];
    const float* Wp0   = (const float*)d_in[6];
    const float* bp0   = (const float*)d_in[7];
    const float* gp0   = (const float*)d_in[8];
    const float* bep0  = (const float*)d_in[9];
    const float* Wp1   = (const float*)d_in[10];
    const float* bp1   = (const float*)d_in[11];
    const float* gp1   = (const float*)d_in[12];
    const float* bep1  = (const float*)d_in[13];
    const float* Wg    = (const float*)d_in[14];
    const float* bg    = (const float*)d_in[15];
    const float* gg    = (const float*)d_in[16];
    const float* beg   = (const float*)d_in[17];
    const float* Wn    = (const float*)d_in[18];
    const float* bn    = (const float*)d_in[19];
    const float* gn    = (const float*)d_in[20];
    const float* ben   = (const float*)d_in[21];
    const float* W1    = (const float*)d_in[22];
    const float* b1    = (const float*)d_in[23];
    const float* g1    = (const float*)d_in[24];
    const float* be1   = (const float*)d_in[25];
    const float* W2    = (const float*)d_in[26];
    const float* b2    = (const float*)d_in[27];

    float* ws  = (float*)d_ws;
    float* acc = ws + ACC_OFF;
    float* hp  = ws + HP_OFF;
    float* hg  = hp;                        // aliased (see k_gemm_hg comment)
    float* cls = ws + CLS_OFF;
    float* nout = (float*)d_out;            // 40000*5
    float* eout = (float*)d_out + 200000;   // 256000*2

    k_zero<<<2048, 256, 0, stream>>>((float4*)acc, ACC_FLOATS / 4);

    k_proj<<<2500, 192, 0, stream>>>(h, Wp0, bp0, gp0, bep0,
                                     Wp1, bp1, gp1, bep1, hp);
    k_scatter<<<96000, 256, 0, stream>>>(hp, src, dst, pos, dist, acc);
    k_gemm_hg<<<1250, 256, 0, stream>>>(hp, acc, Wg, bg, gg, beg, hg);
    k_node_head<<<10000, 256, 0, stream>>>(hg, Wn, bn, gn, ben, nout, cls);
    k_edge_mlp<<<4000, 256, 0, stream>>>(hg, cls, src, dst, polar,
                                         W1, b1, g1, be1, W2, b2, eout);
}